// Round 12
// baseline (1296.099 us; speedup 1.0000x reference)
//
#include <hip/hip_runtime.h>
#include <math.h>

#define D 64
#define LOG2E 1.44269504088896340736f
#define QSCALE (0.35355339059327373f * LOG2E)

typedef float f32x4 __attribute__((ext_vector_type(4)));
typedef float vf4 __attribute__((ext_vector_type(4)));
typedef short bf16x8 __attribute__((ext_vector_type(8)));
typedef unsigned short ushort_t;
typedef unsigned int uint2v __attribute__((ext_vector_type(2)));

#define MF(a, b, c) __builtin_amdgcn_mfma_f32_16x16x32_bf16(a, b, c, 0, 0, 0)

// ---------- helpers ----------
__device__ __forceinline__ float bcast(float x, int i) {
  return __int_as_float(__builtin_amdgcn_readlane(__float_as_int(x), i));
}

// xor-16 partner sum (VALU permlane, no LDS round-trip); bit-exact vs shfl_xor sum.
__device__ __forceinline__ float xs16(float x) {
#if __has_builtin(__builtin_amdgcn_permlane16_swap)
  uint2v a = __builtin_amdgcn_permlane16_swap(__float_as_uint(x), __float_as_uint(x), false, false);
  return __uint_as_float(a[0]) + __uint_as_float(a[1]);
#else
  return x + __shfl_xor(x, 16);
#endif
}
__device__ __forceinline__ float xs32(float x) {
#if __has_builtin(__builtin_amdgcn_permlane32_swap)
  uint2v a = __builtin_amdgcn_permlane32_swap(__float_as_uint(x), __float_as_uint(x), false, false);
  return __uint_as_float(a[0]) + __uint_as_float(a[1]);
#else
  return x + __shfl_xor(x, 32);
#endif
}
__device__ __forceinline__ float qsum(float x) {  // sum over the 4 quads
  return xs32(xs16(x));
}

__device__ __forceinline__ ushort_t f2b(float f) {  // fp32 -> bf16 RTNE (prep only)
  unsigned int u = __float_as_uint(f);
  unsigned int r = (u + 0x7FFFu + ((u >> 16) & 1u)) >> 16;
  return (ushort_t)r;
}
// exact-RTNE packed bf16x2 (bit-identical to scalar f2b; round-4 showed cvt_pk is NOT)
__device__ __forceinline__ unsigned int pkrtne(float lo, float hi) {
  unsigned int a = __float_as_uint(lo);
  unsigned int b = __float_as_uint(hi);
  a = a + 0x7FFFu + ((a >> 16) & 1u);
  b = b + 0x7FFFu + ((b >> 16) & 1u);
  return __builtin_amdgcn_perm(b, a, 0x07060302u);
}
__device__ __forceinline__ f32x4 ld4(const float* __restrict__ p) { return *(const f32x4*)p; }
// pack two C-tiles (even ct, odd ct) into one x32 B-operand pair
__device__ __forceinline__ bf16x8 mkpair(const f32x4& ce, const f32x4& co) {
  union { bf16x8 v; unsigned int w[4]; } u;
  u.w[0] = pkrtne(ce[0], ce[1]);
  u.w[1] = pkrtne(ce[2], ce[3]);
  u.w[2] = pkrtne(co[0], co[1]);
  u.w[3] = pkrtne(co[2], co[3]);
  return u.v;
}
__device__ __forceinline__ f32x4 unpk(bf16x8 p, int half) {  // half 0 = even ct, 1 = odd ct
  union { bf16x8 v; unsigned int w[4]; } u;
  u.v = p;
  unsigned int w0 = u.w[half * 2], w1 = u.w[half * 2 + 1];
  f32x4 r;
  r[0] = __uint_as_float(w0 << 16);
  r[1] = __uint_as_float(w0 & 0xFFFF0000u);
  r[2] = __uint_as_float(w1 << 16);
  r[3] = __uint_as_float(w1 & 0xFFFF0000u);
  return r;
}

// transposed-layout LayerNorm: x,y are 16 channel values/lane; stats over 64 ch
__device__ __forceinline__ void lnT(const f32x4 (&x)[4], f32x4 (&y)[4],
                                    const float* __restrict__ g, const float* __restrict__ b,
                                    int quad) {
  float s1 = 0.f, s2 = 0.f;
#pragma unroll
  for (int ct = 0; ct < 4; ct++)
#pragma unroll
    for (int r = 0; r < 4; r++) { s1 += x[ct][r]; s2 += x[ct][r] * x[ct][r]; }
  s1 = qsum(s1);
  s2 = qsum(s2);
  float mean = s1 * 0.015625f;
  float var = s2 * 0.015625f - mean * mean;
  float rs = rsqrtf(var + 1e-5f);
#pragma unroll
  for (int ct = 0; ct < 4; ct++) {
    f32x4 gv = ld4(g + 16 * ct + 4 * quad);
    f32x4 bv = ld4(b + 16 * ct + 4 * quad);
#pragma unroll
    for (int r = 0; r < 4; r++) y[ct][r] = (x[ct][r] - mean) * rs * gv[r] + bv[r];
  }
}

// gather features+pos (masked) + LN(sa_ln1) -> t (residual) and packed x0/x1
__device__ __forceinline__ void gatherLN(const float* __restrict__ features,
                                         const float* __restrict__ pos_emb, int id, bool vd,
                                         int S, const float* __restrict__ g,
                                         const float* __restrict__ b, int quad,
                                         f32x4 (&t)[4], bf16x8& x0, bf16x8& x1, int N) {
  f32x4 y[4];
  const float* fp = features + (size_t)min(id, N - 1) * 64;
#pragma unroll
  for (int ct = 0; ct < 4; ct++) {
    f32x4 f = ld4(fp + 16 * ct + 4 * quad);
    f32x4 pv = ld4(pos_emb + S * 64 + 16 * ct + 4 * quad);
#pragma unroll
    for (int r = 0; r < 4; r++) t[ct][r] = vd ? (f[r] + pv[r]) : 0.f;
  }
  lnT(t, y, g, b, quad);
  x0 = mkpair(y[0], y[1]);
  x1 = mkpair(y[2], y[3]);
}

// ---------- prep: pack weights as x32 A-frags + zero the CSR count region ----------
__global__ void prep_kernel(const float* __restrict__ si, const float* __restrict__ so,
                            const float* __restrict__ w1s, const float* __restrict__ w2s,
                            const float* __restrict__ ci, const float* __restrict__ co,
                            const float* __restrict__ w1c, const float* __restrict__ w2c,
                            const float* __restrict__ iw, const float* __restrict__ av,
                            float* __restrict__ ws, unsigned int* __restrict__ zp, int zn) {
  int t = blockIdx.x * blockDim.x + threadIdx.x;
  ushort_t* bw = (ushort_t*)(ws + 33280);
  if (t < 98304) {
    const float* src;
    int base, cs;
    int l = t;
    if      (l < 12288) { src = si;  base = 0;     cs = 6; }
    else if (l < 16384) { src = so;  base = 12288; cs = 6; l -= 12288; }
    else if (l < 32768) { src = w1s; base = 16384; cs = 6; l -= 16384; }
    else if (l < 49152) { src = w2s; base = 32768; cs = 8; l -= 32768; }
    else if (l < 61440) { src = ci;  base = 49152; cs = 6; l -= 49152; }
    else if (l < 65536) { src = co;  base = 61440; cs = 6; l -= 61440; }
    else if (l < 81920) { src = w1c; base = 65536; cs = 6; l -= 65536; }
    else                { src = w2c; base = 81920; cs = 8; l -= 81920; }
    int c = l >> cs, k = l & ((1 << cs) - 1);
    int T = (1 << cs) >> 5;
    int ct = c >> 4, m = c & 15, tt = k >> 5, rem = k & 31;
    int quad = (rem >> 2) & 3;
    int j = (((rem >> 4) & 1) << 2) | (rem & 3);
    bw[base + (size_t)((ct * T + tt) * 64 + quad * 16 + m) * 8 + j] = f2b(src[l]);
  } else if (t < 131072) {
    int l = t - 98304;
    int c = l >> 6, k = l & 63;
    ws[(k >> 2) * 2048 + c * 4 + (k & 3)] = iw[l];
  } else if (t < 131584) {
    int l = t - 131072;
    int h = l >> 6, k = l & 63;
    float acc = 0.f;
    for (int c = 0; c < 64; c++) acc += av[h * 64 + c] * iw[(h * 64 + c) * 64 + k];
    ws[32768 + h * 64 + k] = acc;
  } else if (t - 131584 < zn) {
    zp[t - 131584] = 0u;  // zero CSR count region (folded launch)
  }
}

// ================== literal-index macros (straight-line code, no dynamic indexing) ==================
#define SC1(KARR, QF, CT, KS, P, VB)                                                    \
  { f32x4 kv_ = unpk(KARR[KS][(CT) >> 1], (CT) & 1);                                    \
    float sp_ = QF[CT][0] * kv_[0] + QF[CT][1] * kv_[1] + QF[CT][2] * kv_[2] +          \
                QF[CT][3] * kv_[3];                                                     \
    sp_ = xs16(sp_);                                                                    \
    P = (((VB) >> (KS)) & 1) ? sp_ : -1e30f; }

#define PV1(VARR, CT, KS, P, ACC)                                                       \
  { f32x4 vv_ = unpk(VARR[KS][(CT) >> 1], (CT) & 1);                                    \
    _Pragma("unroll") for (int r = 0; r < 4; r++) ACC[r] = fmaf(P, vv_[r], ACC[r]); }

#define ATT_CT(KARR, VARR, QF, CT, OD, VB)                                              \
  {                                                                                     \
    float p0, p1, p2, p3, p4;                                                           \
    SC1(KARR, QF, CT, 0, p0, VB); SC1(KARR, QF, CT, 1, p1, VB);                         \
    SC1(KARR, QF, CT, 2, p2, VB); SC1(KARR, QF, CT, 3, p3, VB);                         \
    SC1(KARR, QF, CT, 4, p4, VB);                                                       \
    float mx_ = fmaxf(fmaxf(fmaxf(p0, p1), fmaxf(p2, p3)), p4);                         \
    p0 = exp2f(p0 - mx_); p1 = exp2f(p1 - mx_); p2 = exp2f(p2 - mx_);                   \
    p3 = exp2f(p3 - mx_); p4 = exp2f(p4 - mx_);                                         \
    float ri_ = 1.0f / (p0 + p1 + p2 + p3 + p4);                                        \
    p0 *= ri_; p1 *= ri_; p2 *= ri_; p3 *= ri_; p4 *= ri_;                              \
    OD = (f32x4){0.f, 0.f, 0.f, 0.f};                                                   \
    PV1(VARR, CT, 0, p0, OD); PV1(VARR, CT, 1, p1, OD); PV1(VARR, CT, 2, p2, OD);       \
    PV1(VARR, CT, 3, p3, OD); PV1(VARR, CT, 4, p4, OD);                                 \
  }

// stage A for literal S, BOTH groups: one set of weight loads feeds 2 groups' MFMAs
#define KV2(S)                                                                          \
  {                                                                                     \
    f32x4 tA[4], tB[4];                                                                 \
    bf16x8 xA0, xA1, xB0, xB1;                                                          \
    gatherLN(features, pos_emb, idsA[S], (vbA >> (S)) & 1, (S), sa_ln1_g, sa_ln1_b,     \
             quad, tA, xA0, xA1, N);                                                    \
    gatherLN(features, pos_emb, idsB[S], (vbB >> (S)) & 1, (S), sa_ln1_g, sa_ln1_b,     \
             quad, tB, xB0, xB1, N);                                                    \
    f32x4 ktA[4], vtA[4], ktB[4], vtB[4];                                               \
    _Pragma("unroll")                                                                   \
    for (int ct = 0; ct < 4; ct++) {                                                    \
      bf16x8 wk0 = WSI[((4 + ct) * 2 + 0) * 64 + lane];                                 \
      bf16x8 wk1 = WSI[((4 + ct) * 2 + 1) * 64 + lane];                                 \
      bf16x8 wv0 = WSI[((8 + ct) * 2 + 0) * 64 + lane];                                 \
      bf16x8 wv1 = WSI[((8 + ct) * 2 + 1) * 64 + lane];                                 \
      f32x4 bbk = ld4(self_in_b + 64 + 16 * ct + 4 * quad);                             \
      f32x4 bbv = ld4(self_in_b + 128 + 16 * ct + 4 * quad);                            \
      f32x4 c = {0.f, 0.f, 0.f, 0.f};                                                   \
      c = MF(wk0, xA0, c); c = MF(wk1, xA1, c);                                         \
      _Pragma("unroll") for (int r = 0; r < 4; r++) ktA[ct][r] = c[r] + bbk[r];         \
      c = (f32x4){0.f, 0.f, 0.f, 0.f};                                                  \
      c = MF(wk0, xB0, c); c = MF(wk1, xB1, c);                                         \
      _Pragma("unroll") for (int r = 0; r < 4; r++) ktB[ct][r] = c[r] + bbk[r];         \
      c = (f32x4){0.f, 0.f, 0.f, 0.f};                                                  \
      c = MF(wv0, xA0, c); c = MF(wv1, xA1, c);                                         \
      _Pragma("unroll") for (int r = 0; r < 4; r++) vtA[ct][r] = c[r] + bbv[r];         \
      c = (f32x4){0.f, 0.f, 0.f, 0.f};                                                  \
      c = MF(wv0, xB0, c); c = MF(wv1, xB1, c);                                         \
      _Pragma("unroll") for (int r = 0; r < 4; r++) vtB[ct][r] = c[r] + bbv[r];         \
    }                                                                                   \
    KpA[S][0] = mkpair(ktA[0], ktA[1]); KpA[S][1] = mkpair(ktA[2], ktA[3]);             \
    VpA[S][0] = mkpair(vtA[0], vtA[1]); VpA[S][1] = mkpair(vtA[2], vtA[3]);             \
    KpB[S][0] = mkpair(ktB[0], ktB[1]); KpB[S][1] = mkpair(ktB[2], ktB[3]);             \
    VpB[S][0] = mkpair(vtB[0], vtB[1]); VpB[S][1] = mkpair(vtB[2], vtB[3]);             \
  }

// stage B for literal S, BOTH groups: shared WSI/WSO loads; per-group attention
#define Q2(S)                                                                           \
  {                                                                                     \
    f32x4 tA[4], tB[4];                                                                 \
    bf16x8 xA0, xA1, xB0, xB1;                                                          \
    gatherLN(features, pos_emb, idsA[S], (vbA >> (S)) & 1, (S), sa_ln1_g, sa_ln1_b,     \
             quad, tA, xA0, xA1, N);                                                    \
    gatherLN(features, pos_emb, idsB[S], (vbB >> (S)) & 1, (S), sa_ln1_g, sa_ln1_b,     \
             quad, tB, xB0, xB1, N);                                                    \
    f32x4 qfA[4], qfB[4];                                                               \
    _Pragma("unroll")                                                                   \
    for (int ct = 0; ct < 4; ct++) {                                                    \
      bf16x8 w0 = WSI[(ct * 2 + 0) * 64 + lane];                                        \
      bf16x8 w1 = WSI[(ct * 2 + 1) * 64 + lane];                                        \
      f32x4 bb = ld4(self_in_b + 16 * ct + 4 * quad);                                   \
      f32x4 c = {0.f, 0.f, 0.f, 0.f};                                                   \
      c = MF(w0, xA0, c); c = MF(w1, xA1, c);                                           \
      _Pragma("unroll") for (int r = 0; r < 4; r++) qfA[ct][r] = (c[r] + bb[r]) * QSCALE; \
      c = (f32x4){0.f, 0.f, 0.f, 0.f};                                                  \
      c = MF(w0, xB0, c); c = MF(w1, xB1, c);                                           \
      _Pragma("unroll") for (int r = 0; r < 4; r++) qfB[ct][r] = (c[r] + bb[r]) * QSCALE; \
    }                                                                                   \
    f32x4 oA0, oA1, oA2, oA3, oB0, oB1, oB2, oB3;                                       \
    ATT_CT(KpA, VpA, qfA, 0, oA0, vbA); ATT_CT(KpA, VpA, qfA, 1, oA1, vbA);             \
    ATT_CT(KpA, VpA, qfA, 2, oA2, vbA); ATT_CT(KpA, VpA, qfA, 3, oA3, vbA);             \
    ATT_CT(KpB, VpB, qfB, 0, oB0, vbB); ATT_CT(KpB, VpB, qfB, 1, oB1, vbB);             \
    ATT_CT(KpB, VpB, qfB, 2, oB2, vbB); ATT_CT(KpB, VpB, qfB, 3, oB3, vbB);             \
    bf16x8 opA0 = mkpair(oA0, oA1), opA1 = mkpair(oA2, oA3);                            \
    bf16x8 opB0 = mkpair(oB0, oB1), opB1 = mkpair(oB2, oB3);                            \
    const bool vdA = (vbA >> (S)) & 1, vdB = (vbB >> (S)) & 1;                          \
    f32x4 tpA[4], tpB[4];                                                               \
    _Pragma("unroll")                                                                   \
    for (int ct = 0; ct < 4; ct++) {                                                    \
      bf16x8 w0 = WSO[(ct * 2 + 0) * 64 + lane];                                        \
      bf16x8 w1 = WSO[(ct * 2 + 1) * 64 + lane];                                        \
      f32x4 bb = ld4(self_out_b + 16 * ct + 4 * quad);                                  \
      f32x4 c = {0.f, 0.f, 0.f, 0.f};                                                   \
      c = MF(w0, opA0, c); c = MF(w1, opA1, c);                                         \
      _Pragma("unroll") for (int r = 0; r < 4; r++) {                                   \
        float tp_ = c[r] + bb[r] + tA[ct][r];                                           \
        tpA[ct][r] = tp_;                                                               \
        poolA[ct][r] += vdA ? tp_ : 0.f;                                                \
      }                                                                                 \
      c = (f32x4){0.f, 0.f, 0.f, 0.f};                                                  \
      c = MF(w0, opB0, c); c = MF(w1, opB1, c);                                         \
      _Pragma("unroll") for (int r = 0; r < 4; r++) {                                   \
        float tp_ = c[r] + bb[r] + tB[ct][r];                                           \
        tpB[ct][r] = tp_;                                                               \
        poolB[ct][r] += vdB ? tp_ : 0.f;                                                \
      }                                                                                 \
    }                                                                                   \
    TPA[S][0] = mkpair(tpA[0], tpA[1]); TPA[S][1] = mkpair(tpA[2], tpA[3]);             \
    TPB[S][0] = mkpair(tpB[0], tpB[1]); TPB[S][1] = mkpair(tpB[2], tpB[3]);             \
  }

// cross K/V for literal S, BOTH groups, shared WCI loads
#define CKV2(S)                                                                         \
  {                                                                                     \
    f32x4 ktA[4], vtA[4], ktB[4], vtB[4];                                               \
    _Pragma("unroll")                                                                   \
    for (int ct = 0; ct < 4; ct++) {                                                    \
      bf16x8 wk0 = WCI[((4 + ct) * 2 + 0) * 64 + lane];                                 \
      bf16x8 wk1 = WCI[((4 + ct) * 2 + 1) * 64 + lane];                                 \
      bf16x8 wv0 = WCI[((8 + ct) * 2 + 0) * 64 + lane];                                 \
      bf16x8 wv1 = WCI[((8 + ct) * 2 + 1) * 64 + lane];                                 \
      f32x4 bbk = ld4(cross_in_b + 64 + 16 * ct + 4 * quad);                            \
      f32x4 bbv = ld4(cross_in_b + 128 + 16 * ct + 4 * quad);                           \
      f32x4 c = {0.f, 0.f, 0.f, 0.f};                                                   \
      c = MF(wk0, TPA[S][0], c); c = MF(wk1, TPA[S][1], c);                             \
      _Pragma("unroll") for (int r = 0; r < 4; r++) ktA[ct][r] = c[r] + bbk[r];         \
      c = (f32x4){0.f, 0.f, 0.f, 0.f};                                                  \
      c = MF(wk0, TPB[S][0], c); c = MF(wk1, TPB[S][1], c);                             \
      _Pragma("unroll") for (int r = 0; r < 4; r++) ktB[ct][r] = c[r] + bbk[r];         \
      c = (f32x4){0.f, 0.f, 0.f, 0.f};                                                  \
      c = MF(wv0, TPA[S][0], c); c = MF(wv1, TPA[S][1], c);                             \
      _Pragma("unroll") for (int r = 0; r < 4; r++) vtA[ct][r] = c[r] + bbv[r];         \
      c = (f32x4){0.f, 0.f, 0.f, 0.f};                                                  \
      c = MF(wv0, TPB[S][0], c); c = MF(wv1, TPB[S][1], c);                             \
      _Pragma("unroll") for (int r = 0; r < 4; r++) vtB[ct][r] = c[r] + bbv[r];         \
    }                                                                                   \
    KcA[S][0] = mkpair(ktA[0], ktA[1]); KcA[S][1] = mkpair(ktA[2], ktA[3]);             \
    VcA[S][0] = mkpair(vtA[0], vtA[1]); VcA[S][1] = mkpair(vtA[2], vtA[3]);             \
    KcB[S][0] = mkpair(ktB[0], ktB[1]); KcB[S][1] = mkpair(ktB[2], ktB[3]);             \
    VcB[S][0] = mkpair(vtB[0], vtB[1]); VcB[S][1] = mkpair(vtB[2], vtB[3]);             \
  }

// transposed FF block for BOTH groups: shared W1/W2 loads
__device__ __forceinline__ void ffnT2(f32x4 (&iA)[4], f32x4 (&iB)[4],
                                      const float* __restrict__ g, const float* __restrict__ b,
                                      const bf16x8* __restrict__ W1, const bf16x8* __restrict__ W2,
                                      const float* __restrict__ b1, const float* __restrict__ b2,
                                      int lane, int quad) {
  f32x4 yA[4], yB[4];
  lnT(iA, yA, g, b, quad);
  lnT(iB, yB, g, b, quad);
  bf16x8 xA0 = mkpair(yA[0], yA[1]), xA1 = mkpair(yA[2], yA[3]);
  bf16x8 xB0 = mkpair(yB[0], yB[1]), xB1 = mkpair(yB[2], yB[3]);
  bf16x8 HA[8], HB[8];
#pragma unroll
  for (int ht = 0; ht < 8; ht++) {
    f32x4 hA[2], hB[2];
#pragma unroll
    for (int u = 0; u < 2; u++) {
      int ct = 2 * ht + u;
      bf16x8 w0 = W1[(ct * 2 + 0) * 64 + lane];
      bf16x8 w1 = W1[(ct * 2 + 1) * 64 + lane];
      f32x4 bb = ld4(b1 + 16 * ct + 4 * quad);
      f32x4 c = {0.f, 0.f, 0.f, 0.f};
      c = MF(w0, xA0, c); c = MF(w1, xA1, c);
#pragma unroll
      for (int r = 0; r < 4; r++) {
        float v = c[r] + bb[r];
        hA[u][r] = 0.5f * v * (1.0f + erff(v * 0.70710678118654752440f));
      }
      c = (f32x4){0.f, 0.f, 0.f, 0.f};
      c = MF(w0, xB0, c); c = MF(w1, xB1, c);
#pragma unroll
      for (int r = 0; r < 4; r++) {
        float v = c[r] + bb[r];
        hB[u][r] = 0.5f * v * (1.0f + erff(v * 0.70710678118654752440f));
      }
    }
    HA[ht] = mkpair(hA[0], hA[1]);
    HB[ht] = mkpair(hB[0], hB[1]);
  }
#pragma unroll
  for (int ct = 0; ct < 4; ct++) {
    f32x4 cA = {0.f, 0.f, 0.f, 0.f}, cB = {0.f, 0.f, 0.f, 0.f};
#pragma unroll
    for (int t = 0; t < 8; t++) {
      bf16x8 w = W2[(ct * 8 + t) * 64 + lane];
      cA = MF(w, HA[t], cA);
      cB = MF(w, HB[t], cB);
    }
    f32x4 bb = ld4(b2 + 16 * ct + 4 * quad);
#pragma unroll
    for (int r = 0; r < 4; r++) {
      iA[ct][r] += cA[r] + bb[r];
      iB[ct][r] += cB[r] + bb[r];
    }
  }
}

// a-score for literal H, BOTH groups, shared uvec loads
#define ASC2(H)                                                                         \
  { float spA = 0.f, spB = 0.f;                                                         \
    _Pragma("unroll")                                                                   \
    for (int ct = 0; ct < 4; ct++) {                                                    \
      f32x4 uu = ld4(uvec + (H) * 64 + 16 * ct + 4 * quad);                             \
      _Pragma("unroll")                                                                 \
      for (int r = 0; r < 4; r++) {                                                     \
        spA = fmaf(instA[ct][r], uu[r], spA);                                           \
        spB = fmaf(instB[ct][r], uu[r], spB);                                           \
      }                                                                                 \
    }                                                                                   \
    spA = qsum(spA); spB = qsum(spB);                                                   \
    aA##H = spA > 0.f ? spA : 0.01f * spA;                                              \
    aB##H = spB > 0.f ? spB : 0.01f * spB; }

// ---------- per-edge transformer: one wave = 32 edges (2 groups of 16) ----------
// 2 groups share every weight A-frag load (the measured ~84% per-SIMD stall is L2
// latency on ~176 weight loads/wave at 1 wave/SIMD; sharing halves loads per edge).
// (64,1): 512-reg budget. Spill tripwire: WRITE_SIZE ~42MB clean, >200MB = scratch.
__global__ __launch_bounds__(64, 1)
void edge_kernel(const float* __restrict__ features, const float* __restrict__ pos_emb,
                 const float* __restrict__ self_in_b, const float* __restrict__ self_out_b,
                 const float* __restrict__ cross_in_b, const float* __restrict__ cross_out_b,
                 const float* __restrict__ sa_ln1_g, const float* __restrict__ sa_ln1_b,
                 const float* __restrict__ sa_ln2_g, const float* __restrict__ sa_ln2_b,
                 const float* __restrict__ ca_ln1_g, const float* __restrict__ ca_ln1_b,
                 const float* __restrict__ ca_ln2_g, const float* __restrict__ ca_ln2_b,
                 const float* __restrict__ sa_ff_b1, const float* __restrict__ sa_ff_b2,
                 const float* __restrict__ ca_ff_b1, const float* __restrict__ ca_ff_b2,
                 const int* __restrict__ midx, const int* __restrict__ dstv,
                 const float* __restrict__ ws,
                 float* __restrict__ inst_out, float* __restrict__ a_out, int E, int N) {
  const int lane = threadIdx.x;
  const int quad = lane >> 4, lo = lane & 15;
  const int e0 = blockIdx.x * 32;
  __shared__ float xp[16 * 68];

  const ushort_t* bw = (const ushort_t*)(ws + 33280);
  const bf16x8* WSI = (const bf16x8*)(bw);
  const bf16x8* WSO = (const bf16x8*)(bw + 12288);
  const bf16x8* W1S = (const bf16x8*)(bw + 16384);
  const bf16x8* W2S = (const bf16x8*)(bw + 32768);
  const bf16x8* WCI = (const bf16x8*)(bw + 49152);
  const bf16x8* WCO = (const bf16x8*)(bw + 61440);
  const bf16x8* W1C = (const bf16x8*)(bw + 65536);
  const bf16x8* W2C = (const bf16x8*)(bw + 81920);
  const float* uvec = ws + 32768;

  // per-lane edge meta for both groups (A: e0+lo, B: e0+16+lo)
  const bool geA = (e0 + lo) < E;
  const bool geB = (e0 + 16 + lo) < E;
  const int eIdxA = min(e0 + lo, E - 1);
  const int eIdxB = min(e0 + 16 + lo, E - 1);
  int idsA[5], idsB[5];
  idsA[0] = midx[eIdxA * 5 + 0];
  idsA[1] = midx[eIdxA * 5 + 1];
  idsA[2] = midx[eIdxA * 5 + 2];
  idsA[3] = midx[eIdxA * 5 + 3];
  idsA[4] = midx[eIdxA * 5 + 4];
  idsB[0] = midx[eIdxB * 5 + 0];
  idsB[1] = midx[eIdxB * 5 + 1];
  idsB[2] = midx[eIdxB * 5 + 2];
  idsB[3] = midx[eIdxB * 5 + 3];
  idsB[4] = midx[eIdxB * 5 + 4];
  int vbA = 0, vbB = 0;
  if (idsA[0] != N && geA) vbA |= 1;
  if (idsA[1] != N && geA) vbA |= 2;
  if (idsA[2] != N && geA) vbA |= 4;
  if (idsA[3] != N && geA) vbA |= 8;
  if (idsA[4] != N && geA) vbA |= 16;
  if (idsB[0] != N && geB) vbB |= 1;
  if (idsB[1] != N && geB) vbB |= 2;
  if (idsB[2] != N && geB) vbB |= 4;
  if (idsB[3] != N && geB) vbB |= 8;
  if (idsB[4] != N && geB) vbB |= 16;
  const int nvA = __popc(vbA), nvB = __popc(vbB);
  const int lpA = max(nvA - 1, 0), lpB = max(nvB - 1, 0);
  int lidA = idsA[0];
  lidA = (lpA == 1) ? idsA[1] : lidA;
  lidA = (lpA == 2) ? idsA[2] : lidA;
  lidA = (lpA == 3) ? idsA[3] : lidA;
  lidA = (lpA == 4) ? idsA[4] : lidA;
  int lidB = idsB[0];
  lidB = (lpB == 1) ? idsB[1] : lidB;
  lidB = (lpB == 2) ? idsB[2] : lidB;
  lidB = (lpB == 3) ? idsB[3] : lidB;
  lidB = (lpB == 4) ? idsB[4] : lidB;

  // ---- stage A: K, V for both groups ----
  bf16x8 KpA[5][2], VpA[5][2], KpB[5][2], VpB[5][2];
  KV2(0); KV2(1); KV2(2); KV2(3); KV2(4);

  // ---- stage B: per-qs attention + out-proj + residual + pool + TP, both groups ----
  f32x4 poolA[4], poolB[4];
#pragma unroll
  for (int ct = 0; ct < 4; ct++) {
    poolA[ct] = (f32x4){0.f, 0.f, 0.f, 0.f};
    poolB[ct] = (f32x4){0.f, 0.f, 0.f, 0.f};
  }
  bf16x8 TPA[5][2], TPB[5][2];
  Q2(0); Q2(1); Q2(2); Q2(3); Q2(4);

  f32x4 instA[4], instB[4];
  {
    float rnA = 1.0f / (float)max(nvA, 1);
    float rnB = 1.0f / (float)max(nvB, 1);
#pragma unroll
    for (int ct = 0; ct < 4; ct++)
#pragma unroll
      for (int r = 0; r < 4; r++) {
        instA[ct][r] = poolA[ct][r] * rnA;
        instB[ct][r] = poolB[ct][r] * rnB;
      }
  }

  // ---- FF-sa ----
  ffnT2(instA, instB, sa_ln2_g, sa_ln2_b, W1S, W2S, sa_ff_b1, sa_ff_b2, lane, quad);

  // ---- cross attention ----
  {
    f32x4 tfA[4], tfB[4], xqA[4], xqB[4];
    const bool vdlA = lidA != N, vdlB = lidB != N;
    const float* fpA = features + (size_t)min(lidA, N - 1) * 64;
    const float* fpB = features + (size_t)min(lidB, N - 1) * 64;
#pragma unroll
    for (int ct = 0; ct < 4; ct++) {
      f32x4 fA = ld4(fpA + 16 * ct + 4 * quad);
      f32x4 fB = ld4(fpB + 16 * ct + 4 * quad);
#pragma unroll
      for (int r = 0; r < 4; r++) {
        tfA[ct][r] = vdlA ? fA[r] : 0.f;
        tfB[ct][r] = vdlB ? fB[r] : 0.f;
      }
    }
    lnT(tfA, xqA, ca_ln1_g, ca_ln1_b, quad);
    lnT(tfB, xqB, ca_ln1_g, ca_ln1_b, quad);
    bf16x8 xqA0 = mkpair(xqA[0], xqA[1]), xqA1 = mkpair(xqA[2], xqA[3]);
    bf16x8 xqB0 = mkpair(xqB[0], xqB[1]), xqB1 = mkpair(xqB[2], xqB[3]);
    f32x4 qcA[4], qcB[4];
#pragma unroll
    for (int ct = 0; ct < 4; ct++) {
      bf16x8 w0 = WCI[(ct * 2 + 0) * 64 + lane];
      bf16x8 w1 = WCI[(ct * 2 + 1) * 64 + lane];
      f32x4 bb = ld4(cross_in_b + 16 * ct + 4 * quad);
      f32x4 c = {0.f, 0.f, 0.f, 0.f};
      c = MF(w0, xqA0, c); c = MF(w1, xqA1, c);
#pragma unroll
      for (int r = 0; r < 4; r++) qcA[ct][r] = (c[r] + bb[r]) * QSCALE;
      c = (f32x4){0.f, 0.f, 0.f, 0.f};
      c = MF(w0, xqB0, c); c = MF(w1, xqB1, c);
#pragma unroll
      for (int r = 0; r < 4; r++) qcB[ct][r] = (c[r] + bb[r]) * QSCALE;
    }
    bf16x8 KcA[5][2], VcA[5][2], KcB[5][2], VcB[5][2];
    CKV2(0); CKV2(1); CKV2(2); CKV2(3); CKV2(4);
    f32x4 ccA0, ccA1, ccA2, ccA3, ccB0, ccB1, ccB2, ccB3;
    ATT_CT(KcA, VcA, qcA, 0, ccA0, vbA); ATT_CT(KcA, VcA, qcA, 1, ccA1, vbA);
    ATT_CT(KcA, VcA, qcA, 2, ccA2, vbA); ATT_CT(KcA, VcA, qcA, 3, ccA3, vbA);
    ATT_CT(KcB, VcB, qcB, 0, ccB0, vbB); ATT_CT(KcB, VcB, qcB, 1, ccB1, vbB);
    ATT_CT(KcB, VcB, qcB, 2, ccB2, vbB); ATT_CT(KcB, VcB, qcB, 3, ccB3, vbB);
    bf16x8 cpA0 = mkpair(ccA0, ccA1), cpA1 = mkpair(ccA2, ccA3);
    bf16x8 cpB0 = mkpair(ccB0, ccB1), cpB1 = mkpair(ccB2, ccB3);
#pragma unroll
    for (int ct = 0; ct < 4; ct++) {
      bf16x8 w0 = WCO[(ct * 2 + 0) * 64 + lane];
      bf16x8 w1 = WCO[(ct * 2 + 1) * 64 + lane];
      f32x4 bb = ld4(cross_out_b + 16 * ct + 4 * quad);
      f32x4 c = {0.f, 0.f, 0.f, 0.f};
      c = MF(w0, cpA0, c); c = MF(w1, cpA1, c);
#pragma unroll
      for (int r = 0; r < 4; r++) instA[ct][r] += c[r] + bb[r];
      c = (f32x4){0.f, 0.f, 0.f, 0.f};
      c = MF(w0, cpB0, c); c = MF(w1, cpB1, c);
#pragma unroll
      for (int r = 0; r < 4; r++) instB[ct][r] += c[r] + bb[r];
    }
  }

  // ---- FF-ca ----
  ffnT2(instA, instB, ca_ln2_g, ca_ln2_b, W1C, W2C, ca_ff_b1, ca_ff_b2, lane, quad);

  // ---- a-scores for both groups ----
  float aA0, aA1, aA2, aA3, aA4, aA5, aA6, aA7;
  float aB0, aB1, aB2, aB3, aB4, aB5, aB6, aB7;
  ASC2(0); ASC2(1); ASC2(2); ASC2(3); ASC2(4); ASC2(5); ASC2(6); ASC2(7);
  if (geA && quad < 2) {
    f32x4 st = (quad == 0) ? (f32x4){aA0, aA1, aA2, aA3} : (f32x4){aA4, aA5, aA6, aA7};
    *(f32x4*)(a_out + (size_t)(e0 + lo) * 8 + 4 * quad) = st;
  }
  if (geB && quad < 2) {
    f32x4 st = (quad == 0) ? (f32x4){aB0, aB1, aB2, aB3} : (f32x4){aB4, aB5, aB6, aB7};
    *(f32x4*)(a_out + (size_t)(e0 + 16 + lo) * 8 + 4 * quad) = st;
  }

  // ---- inst_out: LDS transpose + coalesced store, group A then group B ----
#pragma unroll
  for (int ct = 0; ct < 4; ct++)
    *(f32x4*)(&xp[lo * 68 + 16 * ct + 4 * quad]) = instA[ct];
  __syncthreads();
  {
    int er = lane >> 2, cb = (lane & 3) * 16;
    if (e0 + er < E) {
#pragma unroll
      for (int u = 0; u < 4; u++) {
        f32x4 v = *(const f32x4*)(&xp[er * 68 + cb + 4 * u]);
        *(f32x4*)(inst_out + (size_t)(e0 + er) * 64 + cb + 4 * u) = v;
      }
    }
  }
  __syncthreads();
#pragma unroll
  for (int ct = 0; ct < 4; ct++)
    *(f32x4*)(&xp[lo * 68 + 16 * ct + 4 * quad]) = instB[ct];
  __syncthreads();
  {
    int er = lane >> 2, cb = (lane & 3) * 16;
    if (e0 + 16 + er < E) {
#pragma unroll
      for (int u = 0; u < 4; u++) {
        f32x4 v = *(const f32x4*)(&xp[er * 68 + cb + 4 * u]);
        *(f32x4*)(inst_out + (size_t)(e0 + 16 + er) * 64 + cb + 4 * u) = v;
      }
    }
  }
}

// ================== CSR-by-dst build (parallel 3-phase scan) ==================
__global__ void csr_count_kernel(const int* __restrict__ dstv, unsigned int* __restrict__ cnt,
                                 int E) {
  int e = blockIdx.x * blockDim.x + threadIdx.x;
  if (e < E) atomicAdd(&cnt[dstv[e]], 1u);
}

__global__ void scan1_kernel(unsigned int* __restrict__ off, unsigned int* __restrict__ bsum,
                             int N) {
  __shared__ unsigned int sd[256];
  int t = threadIdx.x, n = blockIdx.x * 256 + t;
  unsigned int v = (n < N) ? off[n] : 0u;
  sd[t] = v;
  __syncthreads();
  for (int o = 1; o < 256; o <<= 1) {
    unsigned int x = (t >= o) ? sd[t - o] : 0u;
    __syncthreads();
    sd[t] += x;
    __syncthreads();
  }
  if (n < N) off[n] = sd[t] - v;  // local exclusive
  if (t == 255) bsum[blockIdx.x] = sd[255];
}

__global__ void scan2_kernel(unsigned int* __restrict__ bsum, int nb) {
  __shared__ unsigned int sd[1024];
  int t = threadIdx.x;
  unsigned int v = (t < nb) ? bsum[t] : 0u;
  sd[t] = v;
  __syncthreads();
  for (int o = 1; o < 1024; o <<= 1) {
    unsigned int x = (t >= o) ? sd[t - o] : 0u;
    __syncthreads();
    sd[t] += x;
    __syncthreads();
  }
  if (t < nb) bsum[t] = sd[t] - v;  // exclusive
}

__global__ void scan3_kernel(unsigned int* __restrict__ off, unsigned int* __restrict__ cur,
                             const unsigned int* __restrict__ bsum, int N, int E) {
  int n = blockIdx.x * 256 + threadIdx.x;
  if (n < N) {
    unsigned int o = off[n] + bsum[blockIdx.x];
    off[n] = o;
    cur[n] = o;
  }
  if (n == 0) off[N] = (unsigned int)E;
}

__global__ void csr_fill_kernel(const int* __restrict__ dstv, unsigned int* __restrict__ cur,
                                unsigned int* __restrict__ elist, int E) {
  int e = blockIdx.x * blockDim.x + threadIdx.x;
  if (e < E) {
    unsigned int p = atomicAdd(&cur[dstv[e]], 1u);
    elist[p] = (unsigned int)e;
  }
}

// ================== per-node edge-softmax: a -> unnormalized w, sinv[n][h]=1/s ==================
__global__ __launch_bounds__(256)
void att_kernel(const unsigned int* __restrict__ off, const unsigned int* __restrict__ elist,
                float* __restrict__ a, float* __restrict__ sinv, int N) {
  int n = blockIdx.x * blockDim.x + threadIdx.x;
  if (n >= N) return;
  const unsigned int s0 = off[n], s1 = off[n + 1];
  f32x4 m0 = {-3.0e38f, -3.0e38f, -3.0e38f, -3.0e38f}, m1 = m0;
  for (unsigned int i = s0; i < s1; i++) {
    const float* ap = a + (size_t)elist[i] * 8;
    f32x4 x0 = ld4(ap), x1 = ld4(ap + 4);
#pragma unroll
    for (int r = 0; r < 4; r++) { m0[r] = fmaxf(m0[r], x0[r]); m1[r] = fmaxf(m1[r], x1[r]); }
  }
  f32x4 t0 = {0.f, 0.f, 0.f, 0.f}, t1 = t0;
  for (unsigned int i = s0; i < s1; i++) {
    float* ap = a + (size_t)elist[i] * 8;
    f32x4 x0 = ld4(ap), x1 = ld4(ap + 4);
    f32x4 w0, w1;
#pragma unroll
    for (int r = 0; r < 4; r++) {
      w0[r] = __expf(x0[r] - m0[r]);
      w1[r] = __expf(x1[r] - m1[r]);
      t0[r] += w0[r];
      t1[r] += w1[r];
    }
    *(f32x4*)ap = w0;
    *(f32x4*)(ap + 4) = w1;
  }
  f32x4 r0, r1;
#pragma unroll
  for (int r = 0; r < 4; r++) {
    r0[r] = (t0[r] > 0.f) ? 1.0f / t0[r] : 0.f;
    r1[r] = (t1[r] > 0.f) ? 1.0f / t1[r] : 0.f;
  }
  *(f32x4*)(sinv + (size_t)n * 8) = r0;
  *(f32x4*)(sinv + (size_t)n * 8 + 4) = r1;
}

// ================== fused gather: per (h, node) weighted sum + head transform ==================
__global__ __launch_bounds__(256)
void gather_kernel(const float* __restrict__ T_iw, const unsigned int* __restrict__ off,
                   const unsigned int* __restrict__ elist, const float* __restrict__ a,
                   const float* __restrict__ sinv, const float* __restrict__ inst_emb,
                   float* __restrict__ out, int N) {
  const int lane = threadIdx.x & 63;
  const int widx = threadIdx.x >> 6;
  const int h = blockIdx.y;
  const vf4* P = (const vf4*)T_iw;
  vf4 wr[16];
#pragma unroll
  for (int k = 0; k < 16; k++) wr[k] = P[k * 512 + h * 64 + lane];  // W_h[lane][4k..4k+3]
  const int stride = gridDim.x * 4;
  for (int n = blockIdx.x * 4 + widx; n < N; n += stride) {
    const unsigned int s0 = off[n], s1 = off[n + 1];
    float z = 0.f;
    for (unsigned int i = s0; i < s1; i++) {
      unsigned int e = elist[i];
      z = fmaf(a[(size_t)e * 8 + h], inst_emb[(size_t)e * 64 + lane], z);
    }
    z *= sinv[(size_t)n * 8 + h];
    float o = 0.f;
#pragma unroll
    for (int k = 0; k < 16; k++) {
#pragma unroll
      for (int u = 0; u < 4; u++) o = fmaf(bcast(z, k * 4 + u), wr[k][u], o);
    }
    out[(size_t)n * 512 + h * 64 + lane] = o;
  }
}

extern "C" void kernel_launch(void* const* d_in, const int* in_sizes, int n_in,
                              void* d_out, int out_size, void* d_ws, size_t ws_size,
                              hipStream_t stream) {
  const float* features   = (const float*)d_in[0];
  const float* pos_emb    = (const float*)d_in[1];
  const float* self_in_w  = (const float*)d_in[2];
  const float* self_in_b  = (const float*)d_in[3];
  const float* self_out_w = (const float*)d_in[4];
  const float* self_out_b = (const float*)d_in[5];
  const float* cross_in_w = (const float*)d_in[6];
  const float* cross_in_b = (const float*)d_in[7];
  const float* cross_out_w= (const float*)d_in[8];
  const float* cross_out_b= (const float*)d_in[9];
  const float* sa_ln1_g = (const float*)d_in[10];
  const float* sa_ln1_b = (const float*)d_in[11];
  const float* sa_ln2_g = (const float*)d_in[12];
  const float* sa_ln2_b = (const float*)d_in[13];
  const float* ca_ln1_g = (const float*)d_in[14];
  const float* ca_ln1_b = (const float*)d_in[15];
  const float* ca_ln2_g = (const float*)d_in[16];
  const float* ca_ln2_b = (const float*)d_in[17];
  const float* sa_ff_w1 = (const float*)d_in[18];
  const float* sa_ff_b1 = (const float*)d_in[19];
  const float* sa_ff_w2 = (const float*)d_in[20];
  const float* sa_ff_b2 = (const float*)d_in[21];
  const float* ca_ff_w1 = (const float*)d_in[22];
  const float* ca_ff_b1 = (const float*)d_in[23];
  const float* ca_ff_w2 = (const float*)d_in[24];
  const float* ca_ff_b2 = (const float*)d_in[25];
  const float* inst_w   = (const float*)d_in[26];
  const float* attn_vec = (const float*)d_in[27];
  const int* midx = (const int*)d_in[28];
  const int* dstv = (const int*)d_in[29];

  const int N = in_sizes[0] / 64;
  const int E = in_sizes[29];

  // ws floats: [0..32767] T_iw | [32768..33279] u | [33280..82431] bf16 A-frag packs
  //            [131072...] inst_emb[E*64] | a[E*8] | off[N+1] | cur[N] | bsum[1024]
  //            | elist[E] | sinv[N*8]
  float* wsf = (float*)d_ws;
  float* inst_emb = wsf + 131072;
  float* a_arr = inst_emb + (size_t)E * 64;
  unsigned int* off = (unsigned int*)(a_arr + (size_t)E * 8);
  unsigned int* cur = off + (size_t)(N + 1);
  unsigned int* bsum = cur + (size_t)N;
  unsigned int* elist = bsum + 1024;
  float* sinv = (float*)(elist + (size_t)E);

  const int nb1 = (N + 255) / 256;

  // prep + zero CSR count region (folded: saves one launch)
  int zn = N + 1;
  prep_kernel<<<(131584 + zn + 255) / 256, 256, 0, stream>>>(
      self_in_w, self_out_w, sa_ff_w1, sa_ff_w2, cross_in_w, cross_out_w, ca_ff_w1, ca_ff_w2,
      inst_w, attn_vec, wsf, off, zn);

  // CSR build (independent of edge_kernel results)
  csr_count_kernel<<<(E + 255) / 256, 256, 0, stream>>>(dstv, off, E);
  scan1_kernel<<<nb1, 256, 0, stream>>>(off, bsum, N);
  scan2_kernel<<<1, 1024, 0, stream>>>(bsum, nb1);
  scan3_kernel<<<nb1, 256, 0, stream>>>(off, cur, bsum, N, E);
  csr_fill_kernel<<<(E + 255) / 256, 256, 0, stream>>>(dstv, cur, elist, E);

  int nblk = (E + 31) / 32;  // 1 wave/block, 32 edges/wave (2 groups of 16)
  edge_kernel<<<nblk, 64, 0, stream>>>(
      features, pos_emb, self_in_b, self_out_b, cross_in_b, cross_out_b, sa_ln1_g, sa_ln1_b,
      sa_ln2_g, sa_ln2_b, ca_ln1_g, ca_ln1_b, ca_ln2_g, ca_ln2_b, sa_ff_b1, sa_ff_b2, ca_ff_b1,
      ca_ff_b2, midx, dstv, wsf, inst_emb, a_arr, E, N);

  att_kernel<<<(N + 255) / 256, 256, 0, stream>>>(off, elist, a_arr, sinv, N);

  dim3 ggrid(256, 8);
  gather_kernel<<<ggrid, 256, 0, stream>>>(wsf, off, elist, a_arr, sinv, inst_emb,
                                           (float*)d_out, N);
}

// Round 13
// 912.810 us; speedup vs baseline: 1.4199x; 1.4199x over previous
//
#include <hip/hip_runtime.h>
#include <math.h>

#define D 64
#define LOG2E 1.44269504088896340736f
#define QSCALE (0.35355339059327373f * LOG2E)

typedef float f32x4 __attribute__((ext_vector_type(4)));
typedef float vf4 __attribute__((ext_vector_type(4)));
typedef short bf16x8 __attribute__((ext_vector_type(8)));
typedef unsigned short ushort_t;
typedef unsigned int uint2v __attribute__((ext_vector_type(2)));

#define MF(a, b, c) __builtin_amdgcn_mfma_f32_16x16x32_bf16(a, b, c, 0, 0, 0)

// ---------- helpers ----------
__device__ __forceinline__ float bcast(float x, int i) {
  return __int_as_float(__builtin_amdgcn_readlane(__float_as_int(x), i));
}

// xor-16 partner sum (VALU permlane, no LDS round-trip); bit-exact vs shfl_xor sum.
__device__ __forceinline__ float xs16(float x) {
#if __has_builtin(__builtin_amdgcn_permlane16_swap)
  uint2v a = __builtin_amdgcn_permlane16_swap(__float_as_uint(x), __float_as_uint(x), false, false);
  return __uint_as_float(a[0]) + __uint_as_float(a[1]);
#else
  return x + __shfl_xor(x, 16);
#endif
}
__device__ __forceinline__ float xs32(float x) {
#if __has_builtin(__builtin_amdgcn_permlane32_swap)
  uint2v a = __builtin_amdgcn_permlane32_swap(__float_as_uint(x), __float_as_uint(x), false, false);
  return __uint_as_float(a[0]) + __uint_as_float(a[1]);
#else
  return x + __shfl_xor(x, 32);
#endif
}
__device__ __forceinline__ float qsum(float x) {  // sum over the 4 quads
  return xs32(xs16(x));
}

__device__ __forceinline__ ushort_t f2b(float f) {  // fp32 -> bf16 RTNE (prep only)
  unsigned int u = __float_as_uint(f);
  unsigned int r = (u + 0x7FFFu + ((u >> 16) & 1u)) >> 16;
  return (ushort_t)r;
}
// exact-RTNE packed bf16x2 (bit-identical to scalar f2b; round-4 showed cvt_pk is NOT)
__device__ __forceinline__ unsigned int pkrtne(float lo, float hi) {
  unsigned int a = __float_as_uint(lo);
  unsigned int b = __float_as_uint(hi);
  a = a + 0x7FFFu + ((a >> 16) & 1u);
  b = b + 0x7FFFu + ((b >> 16) & 1u);
  return __builtin_amdgcn_perm(b, a, 0x07060302u);
}
__device__ __forceinline__ f32x4 ld4(const float* __restrict__ p) { return *(const f32x4*)p; }
// pack two C-tiles (even ct, odd ct) into one x32 B-operand pair
__device__ __forceinline__ bf16x8 mkpair(const f32x4& ce, const f32x4& co) {
  union { bf16x8 v; unsigned int w[4]; } u;
  u.w[0] = pkrtne(ce[0], ce[1]);
  u.w[1] = pkrtne(ce[2], ce[3]);
  u.w[2] = pkrtne(co[0], co[1]);
  u.w[3] = pkrtne(co[2], co[3]);
  return u.v;
}
__device__ __forceinline__ f32x4 unpk(bf16x8 p, int half) {  // half 0 = even ct, 1 = odd ct
  union { bf16x8 v; unsigned int w[4]; } u;
  u.v = p;
  unsigned int w0 = u.w[half * 2], w1 = u.w[half * 2 + 1];
  f32x4 r;
  r[0] = __uint_as_float(w0 << 16);
  r[1] = __uint_as_float(w0 & 0xFFFF0000u);
  r[2] = __uint_as_float(w1 << 16);
  r[3] = __uint_as_float(w1 & 0xFFFF0000u);
  return r;
}

// transposed-layout LayerNorm: x,y are 16 channel values/lane; stats over 64 ch
__device__ __forceinline__ void lnT(const f32x4 (&x)[4], f32x4 (&y)[4],
                                    const float* __restrict__ g, const float* __restrict__ b,
                                    int quad) {
  float s1 = 0.f, s2 = 0.f;
#pragma unroll
  for (int ct = 0; ct < 4; ct++)
#pragma unroll
    for (int r = 0; r < 4; r++) { s1 += x[ct][r]; s2 += x[ct][r] * x[ct][r]; }
  s1 = qsum(s1);
  s2 = qsum(s2);
  float mean = s1 * 0.015625f;
  float var = s2 * 0.015625f - mean * mean;
  float rs = rsqrtf(var + 1e-5f);
#pragma unroll
  for (int ct = 0; ct < 4; ct++) {
    f32x4 gv = ld4(g + 16 * ct + 4 * quad);
    f32x4 bv = ld4(b + 16 * ct + 4 * quad);
#pragma unroll
    for (int r = 0; r < 4; r++) y[ct][r] = (x[ct][r] - mean) * rs * gv[r] + bv[r];
  }
}

// ---------- prep: pack weights as x32 A-frags + zero the CSR count region ----------
__global__ void prep_kernel(const float* __restrict__ si, const float* __restrict__ so,
                            const float* __restrict__ w1s, const float* __restrict__ w2s,
                            const float* __restrict__ ci, const float* __restrict__ co,
                            const float* __restrict__ w1c, const float* __restrict__ w2c,
                            const float* __restrict__ iw, const float* __restrict__ av,
                            float* __restrict__ ws, unsigned int* __restrict__ zp, int zn) {
  int t = blockIdx.x * blockDim.x + threadIdx.x;
  ushort_t* bw = (ushort_t*)(ws + 33280);
  if (t < 98304) {
    const float* src;
    int base, cs;
    int l = t;
    if      (l < 12288) { src = si;  base = 0;     cs = 6; }
    else if (l < 16384) { src = so;  base = 12288; cs = 6; l -= 12288; }
    else if (l < 32768) { src = w1s; base = 16384; cs = 6; l -= 16384; }
    else if (l < 49152) { src = w2s; base = 32768; cs = 8; l -= 32768; }
    else if (l < 61440) { src = ci;  base = 49152; cs = 6; l -= 49152; }
    else if (l < 65536) { src = co;  base = 61440; cs = 6; l -= 61440; }
    else if (l < 81920) { src = w1c; base = 65536; cs = 6; l -= 65536; }
    else                { src = w2c; base = 81920; cs = 8; l -= 81920; }
    int c = l >> cs, k = l & ((1 << cs) - 1);
    int T = (1 << cs) >> 5;
    int ct = c >> 4, m = c & 15, tt = k >> 5, rem = k & 31;
    int quad = (rem >> 2) & 3;
    int j = (((rem >> 4) & 1) << 2) | (rem & 3);
    bw[base + (size_t)((ct * T + tt) * 64 + quad * 16 + m) * 8 + j] = f2b(src[l]);
  } else if (t < 131072) {
    int l = t - 98304;
    int c = l >> 6, k = l & 63;
    ws[(k >> 2) * 2048 + c * 4 + (k & 3)] = iw[l];
  } else if (t < 131584) {
    int l = t - 131072;
    int h = l >> 6, k = l & 63;
    float acc = 0.f;
    for (int c = 0; c < 64; c++) acc += av[h * 64 + c] * iw[(h * 64 + c) * 64 + k];
    ws[32768 + h * 64 + k] = acc;
  } else if (t - 131584 < zn) {
    zp[t - 131584] = 0u;  // zero CSR count region (folded launch)
  }
}

// ================== literal-index macros (straight-line code, no dynamic indexing) ==================
#define SC1(KARR, QF, CT, KS, P)                                                        \
  { f32x4 kv_ = unpk(KARR[KS][(CT) >> 1], (CT) & 1);                                    \
    float sp_ = QF[CT][0] * kv_[0] + QF[CT][1] * kv_[1] + QF[CT][2] * kv_[2] +          \
                QF[CT][3] * kv_[3];                                                     \
    sp_ = xs16(sp_);                                                                    \
    P = ((vb >> (KS)) & 1) ? sp_ : -1e30f; }

#define PV1(VARR, CT, KS, P, ACC)                                                       \
  { f32x4 vv_ = unpk(VARR[KS][(CT) >> 1], (CT) & 1);                                    \
    _Pragma("unroll") for (int r = 0; r < 4; r++) ACC[r] = fmaf(P, vv_[r], ACC[r]); }

#define ATT_CT(KARR, VARR, QF, CT, OD)                                                  \
  {                                                                                     \
    float p0, p1, p2, p3, p4;                                                           \
    SC1(KARR, QF, CT, 0, p0); SC1(KARR, QF, CT, 1, p1); SC1(KARR, QF, CT, 2, p2);       \
    SC1(KARR, QF, CT, 3, p3); SC1(KARR, QF, CT, 4, p4);                                 \
    float mx_ = fmaxf(fmaxf(fmaxf(p0, p1), fmaxf(p2, p3)), p4);                         \
    p0 = exp2f(p0 - mx_); p1 = exp2f(p1 - mx_); p2 = exp2f(p2 - mx_);                   \
    p3 = exp2f(p3 - mx_); p4 = exp2f(p4 - mx_);                                         \
    float ri_ = 1.0f / (p0 + p1 + p2 + p3 + p4);                                        \
    p0 *= ri_; p1 *= ri_; p2 *= ri_; p3 *= ri_; p4 *= ri_;                              \
    OD = (f32x4){0.f, 0.f, 0.f, 0.f};                                                   \
    PV1(VARR, CT, 0, p0, OD); PV1(VARR, CT, 1, p1, OD); PV1(VARR, CT, 2, p2, OD);       \
    PV1(VARR, CT, 3, p3, OD); PV1(VARR, CT, 4, p4, OD);                                 \
  }

#define KV_STAGE(S)                                                                     \
  {                                                                                     \
    f32x4 t[4], y[4];                                                                   \
    const bool vd = (vb >> (S)) & 1;                                                    \
    const float* fp = features + (size_t)min(ids[S], N - 1) * 64;                       \
    _Pragma("unroll")                                                                   \
    for (int ct = 0; ct < 4; ct++) {                                                    \
      f32x4 f = ld4(fp + 16 * ct + 4 * quad);                                           \
      f32x4 pv = ld4(pos_emb + (S) * 64 + 16 * ct + 4 * quad);                          \
      _Pragma("unroll")                                                                 \
      for (int r = 0; r < 4; r++) t[ct][r] = vd ? (f[r] + pv[r]) : 0.f;                 \
    }                                                                                   \
    lnT(t, y, sa_ln1_g, sa_ln1_b, quad);                                                \
    bf16x8 xl0 = mkpair(y[0], y[1]), xl1 = mkpair(y[2], y[3]);                          \
    f32x4 kt[4], vt[4];                                                                 \
    _Pragma("unroll")                                                                   \
    for (int ct = 0; ct < 4; ct++) {                                                    \
      f32x4 c = {0.f, 0.f, 0.f, 0.f};                                                   \
      c = MF(WSI[((4 + ct) * 2 + 0) * 64 + lane], xl0, c);                              \
      c = MF(WSI[((4 + ct) * 2 + 1) * 64 + lane], xl1, c);                              \
      f32x4 bb = ld4(self_in_b + 64 + 16 * ct + 4 * quad);                              \
      _Pragma("unroll")                                                                 \
      for (int r = 0; r < 4; r++) kt[ct][r] = c[r] + bb[r];                             \
      f32x4 c2 = {0.f, 0.f, 0.f, 0.f};                                                  \
      c2 = MF(WSI[((8 + ct) * 2 + 0) * 64 + lane], xl0, c2);                            \
      c2 = MF(WSI[((8 + ct) * 2 + 1) * 64 + lane], xl1, c2);                            \
      f32x4 bb2 = ld4(self_in_b + 128 + 16 * ct + 4 * quad);                            \
      _Pragma("unroll")                                                                 \
      for (int r = 0; r < 4; r++) vt[ct][r] = c2[r] + bb2[r];                           \
    }                                                                                   \
    Kp[S][0] = mkpair(kt[0], kt[1]); Kp[S][1] = mkpair(kt[2], kt[3]);                   \
    Vp[S][0] = mkpair(vt[0], vt[1]); Vp[S][1] = mkpair(vt[2], vt[3]);                   \
  }

#define Q_STAGE(S)                                                                      \
  {                                                                                     \
    const bool vd = (vb >> (S)) & 1;                                                    \
    const float* fp = features + (size_t)min(ids[S], N - 1) * 64;                       \
    f32x4 t[4], y[4];                                                                   \
    _Pragma("unroll")                                                                   \
    for (int ct = 0; ct < 4; ct++) {                                                    \
      f32x4 f = ld4(fp + 16 * ct + 4 * quad);                                           \
      f32x4 pv = ld4(pos_emb + (S) * 64 + 16 * ct + 4 * quad);                          \
      _Pragma("unroll")                                                                 \
      for (int r = 0; r < 4; r++) t[ct][r] = vd ? (f[r] + pv[r]) : 0.f;                 \
    }                                                                                   \
    lnT(t, y, sa_ln1_g, sa_ln1_b, quad);                                                \
    bf16x8 xl0 = mkpair(y[0], y[1]), xl1 = mkpair(y[2], y[3]);                          \
    f32x4 qf[4];                                                                        \
    _Pragma("unroll")                                                                   \
    for (int ct = 0; ct < 4; ct++) {                                                    \
      f32x4 c = {0.f, 0.f, 0.f, 0.f};                                                   \
      c = MF(WSI[(ct * 2 + 0) * 64 + lane], xl0, c);                                    \
      c = MF(WSI[(ct * 2 + 1) * 64 + lane], xl1, c);                                    \
      f32x4 bb = ld4(self_in_b + 16 * ct + 4 * quad);                                   \
      _Pragma("unroll")                                                                 \
      for (int r = 0; r < 4; r++) qf[ct][r] = (c[r] + bb[r]) * QSCALE;                  \
    }                                                                                   \
    f32x4 oa0, oa1, oa2, oa3;                                                           \
    ATT_CT(Kp, Vp, qf, 0, oa0); ATT_CT(Kp, Vp, qf, 1, oa1);                             \
    ATT_CT(Kp, Vp, qf, 2, oa2); ATT_CT(Kp, Vp, qf, 3, oa3);                             \
    bf16x8 op0 = mkpair(oa0, oa1), op1 = mkpair(oa2, oa3);                              \
    f32x4 tpc[4];                                                                       \
    _Pragma("unroll")                                                                   \
    for (int ct = 0; ct < 4; ct++) {                                                    \
      f32x4 c = {0.f, 0.f, 0.f, 0.f};                                                   \
      c = MF(WSO[(ct * 2 + 0) * 64 + lane], op0, c);                                    \
      c = MF(WSO[(ct * 2 + 1) * 64 + lane], op1, c);                                    \
      f32x4 bb = ld4(self_out_b + 16 * ct + 4 * quad);                                  \
      _Pragma("unroll")                                                                 \
      for (int r = 0; r < 4; r++) {                                                     \
        float tp_ = c[r] + bb[r] + t[ct][r];                                            \
        tpc[ct][r] = tp_;                                                               \
        pool[ct][r] += vd ? tp_ : 0.f;                                                  \
      }                                                                                 \
    }                                                                                   \
    TP[S][0] = mkpair(tpc[0], tpc[1]); TP[S][1] = mkpair(tpc[2], tpc[3]);               \
  }

#define CKV_STAGE(S)                                                                    \
  {                                                                                     \
    f32x4 kt[4], vt[4];                                                                 \
    _Pragma("unroll")                                                                   \
    for (int ct = 0; ct < 4; ct++) {                                                    \
      f32x4 c = {0.f, 0.f, 0.f, 0.f};                                                   \
      c = MF(WCI[((4 + ct) * 2 + 0) * 64 + lane], TP[S][0], c);                         \
      c = MF(WCI[((4 + ct) * 2 + 1) * 64 + lane], TP[S][1], c);                         \
      f32x4 bb = ld4(cross_in_b + 64 + 16 * ct + 4 * quad);                             \
      _Pragma("unroll")                                                                 \
      for (int r = 0; r < 4; r++) kt[ct][r] = c[r] + bb[r];                             \
      f32x4 c2 = {0.f, 0.f, 0.f, 0.f};                                                  \
      c2 = MF(WCI[((8 + ct) * 2 + 0) * 64 + lane], TP[S][0], c2);                       \
      c2 = MF(WCI[((8 + ct) * 2 + 1) * 64 + lane], TP[S][1], c2);                       \
      f32x4 bb2 = ld4(cross_in_b + 128 + 16 * ct + 4 * quad);                           \
      _Pragma("unroll")                                                                 \
      for (int r = 0; r < 4; r++) vt[ct][r] = c2[r] + bb2[r];                           \
    }                                                                                   \
    Kc[S][0] = mkpair(kt[0], kt[1]); Kc[S][1] = mkpair(kt[2], kt[3]);                   \
    Vc[S][0] = mkpair(vt[0], vt[1]); Vc[S][1] = mkpair(vt[2], vt[3]);                   \
  }

#define FF_H2(CT, HD)                                                                   \
  { f32x4 c = {0.f, 0.f, 0.f, 0.f};                                                     \
    c = MF(W1[((CT) * 2 + 0) * 64 + lane], x0, c);                                      \
    c = MF(W1[((CT) * 2 + 1) * 64 + lane], x1, c);                                      \
    f32x4 bb = ld4(b1 + 16 * (CT) + 4 * quad);                                          \
    _Pragma("unroll")                                                                   \
    for (int r = 0; r < 4; r++) {                                                       \
      float v = c[r] + bb[r];                                                           \
      HD[r] = 0.5f * v * (1.0f + erff(v * 0.70710678118654752440f));                    \
    } }

#define FF_O(CT)                                                                        \
  { f32x4 c = {0.f, 0.f, 0.f, 0.f};                                                     \
    c = MF(W2[((CT) * 8 + 0) * 64 + lane], Hp0, c);                                     \
    c = MF(W2[((CT) * 8 + 1) * 64 + lane], Hp1, c);                                     \
    c = MF(W2[((CT) * 8 + 2) * 64 + lane], Hp2, c);                                     \
    c = MF(W2[((CT) * 8 + 3) * 64 + lane], Hp3, c);                                     \
    c = MF(W2[((CT) * 8 + 4) * 64 + lane], Hp4, c);                                     \
    c = MF(W2[((CT) * 8 + 5) * 64 + lane], Hp5, c);                                     \
    c = MF(W2[((CT) * 8 + 6) * 64 + lane], Hp6, c);                                     \
    c = MF(W2[((CT) * 8 + 7) * 64 + lane], Hp7, c);                                     \
    f32x4 bb = ld4(b2 + 16 * (CT) + 4 * quad);                                          \
    _Pragma("unroll")                                                                   \
    for (int r = 0; r < 4; r++) inst[CT][r] += c[r] + bb[r]; }

__device__ __forceinline__ void ffnT(f32x4 (&inst)[4],
                                     const float* __restrict__ g, const float* __restrict__ b,
                                     const bf16x8* __restrict__ W1, const bf16x8* __restrict__ W2,
                                     const float* __restrict__ b1, const float* __restrict__ b2,
                                     int lane, int quad) {
  f32x4 y[4];
  lnT(inst, y, g, b, quad);
  bf16x8 x0 = mkpair(y[0], y[1]), x1 = mkpair(y[2], y[3]);
  f32x4 ha, hb;
  FF_H2(0, ha);  FF_H2(1, hb);  bf16x8 Hp0 = mkpair(ha, hb);
  FF_H2(2, ha);  FF_H2(3, hb);  bf16x8 Hp1 = mkpair(ha, hb);
  FF_H2(4, ha);  FF_H2(5, hb);  bf16x8 Hp2 = mkpair(ha, hb);
  FF_H2(6, ha);  FF_H2(7, hb);  bf16x8 Hp3 = mkpair(ha, hb);
  FF_H2(8, ha);  FF_H2(9, hb);  bf16x8 Hp4 = mkpair(ha, hb);
  FF_H2(10, ha); FF_H2(11, hb); bf16x8 Hp5 = mkpair(ha, hb);
  FF_H2(12, ha); FF_H2(13, hb); bf16x8 Hp6 = mkpair(ha, hb);
  FF_H2(14, ha); FF_H2(15, hb); bf16x8 Hp7 = mkpair(ha, hb);
  FF_O(0); FF_O(1); FF_O(2); FF_O(3);
}

#define ASC(H)                                                                          \
  { float sp = 0.f;                                                                     \
    _Pragma("unroll")                                                                   \
    for (int ct = 0; ct < 4; ct++) {                                                    \
      f32x4 uu = ld4(uvec + (H) * 64 + 16 * ct + 4 * quad);                             \
      _Pragma("unroll")                                                                 \
      for (int r = 0; r < 4; r++) sp = fmaf(inst[ct][r], uu[r], sp);                    \
    }                                                                                   \
    sp = qsum(sp);                                                                      \
    a##H = sp > 0.f ? sp : 0.01f * sp; }

// ---------- per-edge transformer: one wave = 16 edges, fully register-resident ----------
// (64,1): 512-reg budget, VGPR 252, ZERO spill (rounds 7/8/9/11). Closed directions:
//  * (64,2): arch regs capped 128 -> ~700MB scratch (rounds 0-2, 10)
//  * 32 edges/wave: arch-VGPR hard cap 256 -> spill (round 12)
//  * VALU reduction: no latency effect (round 7; chain/latency-bound)
__global__ __launch_bounds__(64, 1)
void edge_kernel(const float* __restrict__ features, const float* __restrict__ pos_emb,
                 const float* __restrict__ self_in_b, const float* __restrict__ self_out_b,
                 const float* __restrict__ cross_in_b, const float* __restrict__ cross_out_b,
                 const float* __restrict__ sa_ln1_g, const float* __restrict__ sa_ln1_b,
                 const float* __restrict__ sa_ln2_g, const float* __restrict__ sa_ln2_b,
                 const float* __restrict__ ca_ln1_g, const float* __restrict__ ca_ln1_b,
                 const float* __restrict__ ca_ln2_g, const float* __restrict__ ca_ln2_b,
                 const float* __restrict__ sa_ff_b1, const float* __restrict__ sa_ff_b2,
                 const float* __restrict__ ca_ff_b1, const float* __restrict__ ca_ff_b2,
                 const int* __restrict__ midx, const int* __restrict__ dstv,
                 const float* __restrict__ ws,
                 float* __restrict__ inst_out, float* __restrict__ a_out, int E, int N) {
  const int lane = threadIdx.x;
  const int quad = lane >> 4, lo = lane & 15;
  const int e0 = blockIdx.x * 16;
  __shared__ float xp[16 * 68];

  const ushort_t* bw = (const ushort_t*)(ws + 33280);
  const bf16x8* WSI = (const bf16x8*)(bw);
  const bf16x8* WSO = (const bf16x8*)(bw + 12288);
  const bf16x8* W1S = (const bf16x8*)(bw + 16384);
  const bf16x8* W2S = (const bf16x8*)(bw + 32768);
  const bf16x8* WCI = (const bf16x8*)(bw + 49152);
  const bf16x8* WCO = (const bf16x8*)(bw + 61440);
  const bf16x8* W1C = (const bf16x8*)(bw + 65536);
  const bf16x8* W2C = (const bf16x8*)(bw + 81920);
  const float* uvec = ws + 32768;

  const bool ge = (e0 + lo) < E;
  const int eIdx = min(e0 + lo, E - 1);
  int ids[5];
  ids[0] = midx[eIdx * 5 + 0];
  ids[1] = midx[eIdx * 5 + 1];
  ids[2] = midx[eIdx * 5 + 2];
  ids[3] = midx[eIdx * 5 + 3];
  ids[4] = midx[eIdx * 5 + 4];
  int vb = 0;
  if (ids[0] != N && ge) vb |= 1;
  if (ids[1] != N && ge) vb |= 2;
  if (ids[2] != N && ge) vb |= 4;
  if (ids[3] != N && ge) vb |= 8;
  if (ids[4] != N && ge) vb |= 16;
  const int nv = __popc(vb);
  const int lp = max(nv - 1, 0);
  int lid = ids[0];
  lid = (lp == 1) ? ids[1] : lid;
  lid = (lp == 2) ? ids[2] : lid;
  lid = (lp == 3) ? ids[3] : lid;
  lid = (lp == 4) ? ids[4] : lid;

  bf16x8 Kp[5][2], Vp[5][2];
  KV_STAGE(0); KV_STAGE(1); KV_STAGE(2); KV_STAGE(3); KV_STAGE(4);

  f32x4 pool[4];
#pragma unroll
  for (int ct = 0; ct < 4; ct++) pool[ct] = (f32x4){0.f, 0.f, 0.f, 0.f};
  bf16x8 TP[5][2];
  Q_STAGE(0); Q_STAGE(1); Q_STAGE(2); Q_STAGE(3); Q_STAGE(4);

  f32x4 inst[4];
  {
    float rn = 1.0f / (float)max(nv, 1);
#pragma unroll
    for (int ct = 0; ct < 4; ct++)
#pragma unroll
      for (int r = 0; r < 4; r++) inst[ct][r] = pool[ct][r] * rn;
  }

  ffnT(inst, sa_ln2_g, sa_ln2_b, W1S, W2S, sa_ff_b1, sa_ff_b2, lane, quad);

  {
    f32x4 tf[4], xq[4];
    const bool vdl = lid != N;
    const float* fp = features + (size_t)min(lid, N - 1) * 64;
#pragma unroll
    for (int ct = 0; ct < 4; ct++) {
      f32x4 f = ld4(fp + 16 * ct + 4 * quad);
#pragma unroll
      for (int r = 0; r < 4; r++) tf[ct][r] = vdl ? f[r] : 0.f;
    }
    lnT(tf, xq, ca_ln1_g, ca_ln1_b, quad);
    bf16x8 xq0 = mkpair(xq[0], xq[1]), xq1 = mkpair(xq[2], xq[3]);
    f32x4 qcf[4];
#pragma unroll
    for (int ct = 0; ct < 4; ct++) {
      f32x4 c = {0.f, 0.f, 0.f, 0.f};
      c = MF(WCI[(ct * 2 + 0) * 64 + lane], xq0, c);
      c = MF(WCI[(ct * 2 + 1) * 64 + lane], xq1, c);
      f32x4 bb = ld4(cross_in_b + 16 * ct + 4 * quad);
#pragma unroll
      for (int r = 0; r < 4; r++) qcf[ct][r] = (c[r] + bb[r]) * QSCALE;
    }
    bf16x8 Kc[5][2], Vc[5][2];
    CKV_STAGE(0); CKV_STAGE(1); CKV_STAGE(2); CKV_STAGE(3); CKV_STAGE(4);
    f32x4 cc0, cc1, cc2, cc3;
    ATT_CT(Kc, Vc, qcf, 0, cc0); ATT_CT(Kc, Vc, qcf, 1, cc1);
    ATT_CT(Kc, Vc, qcf, 2, cc2); ATT_CT(Kc, Vc, qcf, 3, cc3);
    bf16x8 cp0 = mkpair(cc0, cc1), cp1 = mkpair(cc2, cc3);
#pragma unroll
    for (int ct = 0; ct < 4; ct++) {
      f32x4 c = {0.f, 0.f, 0.f, 0.f};
      c = MF(WCO[(ct * 2 + 0) * 64 + lane], cp0, c);
      c = MF(WCO[(ct * 2 + 1) * 64 + lane], cp1, c);
      f32x4 bb = ld4(cross_out_b + 16 * ct + 4 * quad);
#pragma unroll
      for (int r = 0; r < 4; r++) inst[ct][r] += c[r] + bb[r];
    }
  }

  ffnT(inst, ca_ln2_g, ca_ln2_b, W1C, W2C, ca_ff_b1, ca_ff_b2, lane, quad);

  float a0, a1, a2, a3, a4, a5, a6, a7;
  ASC(0); ASC(1); ASC(2); ASC(3); ASC(4); ASC(5); ASC(6); ASC(7);
  if (ge && quad < 2) {
    f32x4 st = (quad == 0) ? (f32x4){a0, a1, a2, a3} : (f32x4){a4, a5, a6, a7};
    *(f32x4*)(a_out + (size_t)(e0 + lo) * 8 + 4 * quad) = st;
  }

#pragma unroll
  for (int ct = 0; ct < 4; ct++)
    *(f32x4*)(&xp[lo * 68 + 16 * ct + 4 * quad]) = inst[ct];
  __syncthreads();
  {
    int er = lane >> 2, cb = (lane & 3) * 16;
    if (e0 + er < E) {
#pragma unroll
      for (int u = 0; u < 4; u++) {
        f32x4 v = *(const f32x4*)(&xp[er * 68 + cb + 4 * u]);
        *(f32x4*)(inst_out + (size_t)(e0 + er) * 64 + cb + 4 * u) = v;
      }
    }
  }
}

// ================== CSR-by-dst build (parallel 3-phase scan; single-block fused scan
// regressed ~90us in round 10 — serial barriers on one CU) ==================
__global__ void csr_count_kernel(const int* __restrict__ dstv, unsigned int* __restrict__ cnt,
                                 int E) {
  int e = blockIdx.x * blockDim.x + threadIdx.x;
  if (e < E) atomicAdd(&cnt[dstv[e]], 1u);
}

__global__ void scan1_kernel(unsigned int* __restrict__ off, unsigned int* __restrict__ bsum,
                             int N) {
  __shared__ unsigned int sd[256];
  int t = threadIdx.x, n = blockIdx.x * 256 + t;
  unsigned int v = (n < N) ? off[n] : 0u;
  sd[t] = v;
  __syncthreads();
  for (int o = 1; o < 256; o <<= 1) {
    unsigned int x = (t >= o) ? sd[t - o] : 0u;
    __syncthreads();
    sd[t] += x;
    __syncthreads();
  }
  if (n < N) off[n] = sd[t] - v;  // local exclusive
  if (t == 255) bsum[blockIdx.x] = sd[255];
}

__global__ void scan2_kernel(unsigned int* __restrict__ bsum, int nb) {
  __shared__ unsigned int sd[1024];
  int t = threadIdx.x;
  unsigned int v = (t < nb) ? bsum[t] : 0u;
  sd[t] = v;
  __syncthreads();
  for (int o = 1; o < 1024; o <<= 1) {
    unsigned int x = (t >= o) ? sd[t - o] : 0u;
    __syncthreads();
    sd[t] += x;
    __syncthreads();
  }
  if (t < nb) bsum[t] = sd[t] - v;  // exclusive
}

__global__ void scan3_kernel(unsigned int* __restrict__ off, unsigned int* __restrict__ cur,
                             const unsigned int* __restrict__ bsum, int N, int E) {
  int n = blockIdx.x * 256 + threadIdx.x;
  if (n < N) {
    unsigned int o = off[n] + bsum[blockIdx.x];
    off[n] = o;
    cur[n] = o;
  }
  if (n == 0) off[N] = (unsigned int)E;
}

__global__ void csr_fill_kernel(const int* __restrict__ dstv, unsigned int* __restrict__ cur,
                                unsigned int* __restrict__ elist, int E) {
  int e = blockIdx.x * blockDim.x + threadIdx.x;
  if (e < E) {
    unsigned int p = atomicAdd(&cur[dstv[e]], 1u);
    elist[p] = (unsigned int)e;
  }
}

// ================== per-node edge-softmax: a[e][0..7] -> unnormalized w, sinv[n][0..7]=1/s ==================
__global__ __launch_bounds__(256)
void att_kernel(const unsigned int* __restrict__ off, const unsigned int* __restrict__ elist,
                float* __restrict__ a, float* __restrict__ sinv, int N) {
  int n = blockIdx.x * blockDim.x + threadIdx.x;
  if (n >= N) return;
  const unsigned int s0 = off[n], s1 = off[n + 1];
  f32x4 m0 = {-3.0e38f, -3.0e38f, -3.0e38f, -3.0e38f}, m1 = m0;
  for (unsigned int i = s0; i < s1; i++) {
    const float* ap = a + (size_t)elist[i] * 8;
    f32x4 x0 = ld4(ap), x1 = ld4(ap + 4);
#pragma unroll
    for (int r = 0; r < 4; r++) { m0[r] = fmaxf(m0[r], x0[r]); m1[r] = fmaxf(m1[r], x1[r]); }
  }
  f32x4 t0 = {0.f, 0.f, 0.f, 0.f}, t1 = t0;
  for (unsigned int i = s0; i < s1; i++) {
    float* ap = a + (size_t)elist[i] * 8;
    f32x4 x0 = ld4(ap), x1 = ld4(ap + 4);
    f32x4 w0, w1;
#pragma unroll
    for (int r = 0; r < 4; r++) {
      w0[r] = __expf(x0[r] - m0[r]);
      w1[r] = __expf(x1[r] - m1[r]);
      t0[r] += w0[r];
      t1[r] += w1[r];
    }
    *(f32x4*)ap = w0;
    *(f32x4*)(ap + 4) = w1;
  }
  f32x4 r0, r1;
#pragma unroll
  for (int r = 0; r < 4; r++) {
    r0[r] = (t0[r] > 0.f) ? 1.0f / t0[r] : 0.f;
    r1[r] = (t1[r] > 0.f) ? 1.0f / t1[r] : 0.f;
  }
  *(f32x4*)(sinv + (size_t)n * 8) = r0;
  *(f32x4*)(sinv + (size_t)n * 8 + 4) = r1;
}

// ================== fused gather: per (h, node) weighted sum + head transform ==================
__global__ __launch_bounds__(256)
void gather_kernel(const float* __restrict__ T_iw, const unsigned int* __restrict__ off,
                   const unsigned int* __restrict__ elist, const float* __restrict__ a,
                   const float* __restrict__ sinv, const float* __restrict__ inst_emb,
                   float* __restrict__ out, int N) {
  const int lane = threadIdx.x & 63;
  const int widx = threadIdx.x >> 6;
  const int h = blockIdx.y;
  const vf4* P = (const vf4*)T_iw;
  vf4 wr[16];
#pragma unroll
  for (int k = 0; k < 16; k++) wr[k] = P[k * 512 + h * 64 + lane];  // W_h[lane][4k..4k+3]
  const int stride = gridDim.x * 4;
  for (int n = blockIdx.x * 4 + widx; n < N; n += stride) {
    const unsigned int s0 = off[n], s1 = off[n + 1];
    float z = 0.f;
    for (unsigned int i = s0; i < s1; i++) {
      unsigned int e = elist[i];
      z = fmaf(a[(size_t)e * 8 + h], inst_emb[(size_t)e * 64 + lane], z);
    }
    z *= sinv[(size_t)n * 8 + h];
    float o = 0.f;
#pragma unroll
    for (int k = 0; k < 16; k++) {
#pragma unroll
      for (int u = 0; u < 4; u++) o = fmaf(bcast(z, k * 4 + u), wr[k][u], o);
    }
    out[(size_t)n * 512 + h * 64 + lane] = o;
  }
}

extern "C" void kernel_launch(void* const* d_in, const int* in_sizes, int n_in,
                              void* d_out, int out_size, void* d_ws, size_t ws_size,
                              hipStream_t stream) {
  const float* features   = (const float*)d_in[0];
  const float* pos_emb    = (const float*)d_in[1];
  const float* self_in_w  = (const float*)d_in[2];
  const float* self_in_b  = (const float*)d_in[3];
  const float* self_out_w = (const float*)d_in[4];
  const float* self_out_b = (const float*)d_in[5];
  const float* cross_in_w = (const float*)d_in[6];
  const float* cross_in_b = (const float*)d_in[7];
  const float* cross_out_w= (const float*)d_in[8];
  const float* cross_out_b= (const float*)d_in[9];
  const float* sa_ln1_g = (const float*)d_in[10];
  const float* sa_ln1_b = (const float*)d_in[11];
  const float* sa_ln2_g = (const float*)d_in[12];
  const float* sa_ln2_b = (const float*)d_in[13];
  const float* ca_ln1_g = (const float*)d_in[14];
  const float* ca_ln1_b = (const float*)d_in[15];
  const float* ca_ln2_g = (const float*)d_in[16];
  const float* ca_ln2_b = (const float*)d_in[17];
  const float* sa_ff_w1 = (const float*)d_in[18];
  const float* sa_ff_b1 = (const float*)d_in[19];
  const float* sa_ff_w2 = (const float*)d_in[20];
  const float* sa_ff_b2 = (const float*)d_in[21];
  const float* ca_ff_w1 = (const float*)d_in[22];
  const float* ca_ff_b1 = (const float*)d_in[23];
  const float* ca_ff_w2 = (const float*)d_in[24];
  const float* ca_ff_b2 = (const float*)d_in[25];
  const float* inst_w   = (const float*)d_in[26];
  const float* attn_vec = (const float*)d_in[27];
  const int* midx = (const int*)d_in[28];
  const int* dstv = (const int*)d_in[29];

  const int N = in_sizes[0] / 64;
  const int E = in_sizes[29];

  // ws floats: [0..32767] T_iw | [32768..33279] u | [33280..82431] bf16 A-frag packs
  //            [131072...] inst_emb[E*64] | a[E*8] | off[N+1] | cur[N] | bsum[1024]
  //            | elist[E] | sinv[N*8]
  float* wsf = (float*)d_ws;
  float* inst_emb = wsf + 131072;
  float* a_arr = inst_emb + (size_t)E * 64;
  unsigned int* off = (unsigned int*)(a_arr + (size_t)E * 8);
  unsigned int* cur = off + (size_t)(N + 1);
  unsigned int* bsum = cur + (size_t)N;
  unsigned int* elist = bsum + 1024;
  float* sinv = (float*)(elist + (size_t)E);

  const int nb1 = (N + 255) / 256;

  // prep + zero CSR count region (folded: saves one launch)
  int zn = N + 1;
  prep_kernel<<<(131584 + zn + 255) / 256, 256, 0, stream>>>(
      self_in_w, self_out_w, sa_ff_w1, sa_ff_w2, cross_in_w, cross_out_w, ca_ff_w1, ca_ff_w2,
      inst_w, attn_vec, wsf, off, zn);

  // CSR build (independent of edge_kernel results)
  csr_count_kernel<<<(E + 255) / 256, 256, 0, stream>>>(dstv, off, E);
  scan1_kernel<<<nb1, 256, 0, stream>>>(off, bsum, N);
  scan2_kernel<<<1, 1024, 0, stream>>>(bsum, nb1);
  scan3_kernel<<<nb1, 256, 0, stream>>>(off, cur, bsum, N, E);
  csr_fill_kernel<<<(E + 255) / 256, 256, 0, stream>>>(dstv, cur, elist, E);

  int nblk = (E + 15) / 16;  // 1 wave/block, 16 edges/wave
  edge_kernel<<<nblk, 64, 0, stream>>>(
      features, pos_emb, self_in_b, self_out_b, cross_in_b, cross_out_b, sa_ln1_g, sa_ln1_b,
      sa_ln2_g, sa_ln2_b, ca_ln1_g, ca_ln1_b, ca_ln2_g, ca_ln2_b, sa_ff_b1, sa_ff_b2, ca_ff_b1,
      ca_ff_b2, midx, dstv, wsf, inst_emb, a_arr, E, N);

  att_kernel<<<(N + 255) / 256, 256, 0, stream>>>(off, elist, a_arr, sinv, N);

  dim3 ggrid(256, 8);
  gather_kernel<<<ggrid, 256, 0, stream>>>(wsf, off, elist, a_arr, sinv, inst_emb,
                                           (float*)d_out, N);
}

// Round 14
// 888.657 us; speedup vs baseline: 1.4585x; 1.0272x over previous
//
#include <hip/hip_runtime.h>
#include <math.h>

#define D 64
#define LOG2E 1.44269504088896340736f
#define QSCALE (0.35355339059327373f * LOG2E)

typedef float f32x4 __attribute__((ext_vector_type(4)));
typedef float vf4 __attribute__((ext_vector_type(4)));
typedef short bf16x8 __attribute__((ext_vector_type(8)));
typedef unsigned short ushort_t;
typedef unsigned int uint2v __attribute__((ext_vector_type(2)));

#define MF(a, b, c) __builtin_amdgcn_mfma_f32_16x16x32_bf16(a, b, c, 0, 0, 0)

// ---------- helpers ----------
__device__ __forceinline__ float bcast(float x, int i) {
  return __int_as_float(__builtin_amdgcn_readlane(__float_as_int(x), i));
}

// xor-16 partner sum (VALU permlane, no LDS round-trip); bit-exact vs shfl_xor sum.
__device__ __forceinline__ float xs16(float x) {
#if __has_builtin(__builtin_amdgcn_permlane16_swap)
  uint2v a = __builtin_amdgcn_permlane16_swap(__float_as_uint(x), __float_as_uint(x), false, false);
  return __uint_as_float(a[0]) + __uint_as_float(a[1]);
#else
  return x + __shfl_xor(x, 16);
#endif
}
__device__ __forceinline__ float xs32(float x) {
#if __has_builtin(__builtin_amdgcn_permlane32_swap)
  uint2v a = __builtin_amdgcn_permlane32_swap(__float_as_uint(x), __float_as_uint(x), false, false);
  return __uint_as_float(a[0]) + __uint_as_float(a[1]);
#else
  return x + __shfl_xor(x, 32);
#endif
}
__device__ __forceinline__ float qsum(float x) {  // sum over the 4 quads
  return xs32(xs16(x));
}

__device__ __forceinline__ ushort_t f2b(float f) {  // fp32 -> bf16 RTNE (prep only)
  unsigned int u = __float_as_uint(f);
  unsigned int r = (u + 0x7FFFu + ((u >> 16) & 1u)) >> 16;
  return (ushort_t)r;
}
// exact-RTNE packed bf16x2 (bit-identical to scalar f2b; round-4 showed cvt_pk is NOT)
__device__ __forceinline__ unsigned int pkrtne(float lo, float hi) {
  unsigned int a = __float_as_uint(lo);
  unsigned int b = __float_as_uint(hi);
  a = a + 0x7FFFu + ((a >> 16) & 1u);
  b = b + 0x7FFFu + ((b >> 16) & 1u);
  return __builtin_amdgcn_perm(b, a, 0x07060302u);
}
__device__ __forceinline__ f32x4 ld4(const float* __restrict__ p) { return *(const f32x4*)p; }
// pack two C-tiles (even ct, odd ct) into one x32 B-operand pair
__device__ __forceinline__ bf16x8 mkpair(const f32x4& ce, const f32x4& co) {
  union { bf16x8 v; unsigned int w[4]; } u;
  u.w[0] = pkrtne(ce[0], ce[1]);
  u.w[1] = pkrtne(ce[2], ce[3]);
  u.w[2] = pkrtne(co[0], co[1]);
  u.w[3] = pkrtne(co[2], co[3]);
  return u.v;
}
__device__ __forceinline__ f32x4 unpk(bf16x8 p, int half) {  // half 0 = even ct, 1 = odd ct
  union { bf16x8 v; unsigned int w[4]; } u;
  u.v = p;
  unsigned int w0 = u.w[half * 2], w1 = u.w[half * 2 + 1];
  f32x4 r;
  r[0] = __uint_as_float(w0 << 16);
  r[1] = __uint_as_float(w0 & 0xFFFF0000u);
  r[2] = __uint_as_float(w1 << 16);
  r[3] = __uint_as_float(w1 & 0xFFFF0000u);
  return r;
}

// transposed-layout LayerNorm: x,y are 16 channel values/lane; stats over 64 ch
__device__ __forceinline__ void lnT(const f32x4 (&x)[4], f32x4 (&y)[4],
                                    const float* __restrict__ g, const float* __restrict__ b,
                                    int quad) {
  float s1 = 0.f, s2 = 0.f;
#pragma unroll
  for (int ct = 0; ct < 4; ct++)
#pragma unroll
    for (int r = 0; r < 4; r++) { s1 += x[ct][r]; s2 += x[ct][r] * x[ct][r]; }
  s1 = qsum(s1);
  s2 = qsum(s2);
  float mean = s1 * 0.015625f;
  float var = s2 * 0.015625f - mean * mean;
  float rs = rsqrtf(var + 1e-5f);
#pragma unroll
  for (int ct = 0; ct < 4; ct++) {
    f32x4 gv = ld4(g + 16 * ct + 4 * quad);
    f32x4 bv = ld4(b + 16 * ct + 4 * quad);
#pragma unroll
    for (int r = 0; r < 4; r++) y[ct][r] = (x[ct][r] - mean) * rs * gv[r] + bv[r];
  }
}

// ---------- prep: pack weights as x32 A-frags + zero the CSR count region ----------
__global__ void prep_kernel(const float* __restrict__ si, const float* __restrict__ so,
                            const float* __restrict__ w1s, const float* __restrict__ w2s,
                            const float* __restrict__ ci, const float* __restrict__ co,
                            const float* __restrict__ w1c, const float* __restrict__ w2c,
                            const float* __restrict__ iw, const float* __restrict__ av,
                            float* __restrict__ ws, unsigned int* __restrict__ zp, int zn) {
  int t = blockIdx.x * blockDim.x + threadIdx.x;
  ushort_t* bw = (ushort_t*)(ws + 33280);
  if (t < 98304) {
    const float* src;
    int base, cs;
    int l = t;
    if      (l < 12288) { src = si;  base = 0;     cs = 6; }
    else if (l < 16384) { src = so;  base = 12288; cs = 6; l -= 12288; }
    else if (l < 32768) { src = w1s; base = 16384; cs = 6; l -= 16384; }
    else if (l < 49152) { src = w2s; base = 32768; cs = 8; l -= 32768; }
    else if (l < 61440) { src = ci;  base = 49152; cs = 6; l -= 49152; }
    else if (l < 65536) { src = co;  base = 61440; cs = 6; l -= 61440; }
    else if (l < 81920) { src = w1c; base = 65536; cs = 6; l -= 65536; }
    else                { src = w2c; base = 81920; cs = 8; l -= 81920; }
    int c = l >> cs, k = l & ((1 << cs) - 1);
    int T = (1 << cs) >> 5;
    int ct = c >> 4, m = c & 15, tt = k >> 5, rem = k & 31;
    int quad = (rem >> 2) & 3;
    int j = (((rem >> 4) & 1) << 2) | (rem & 3);
    bw[base + (size_t)((ct * T + tt) * 64 + quad * 16 + m) * 8 + j] = f2b(src[l]);
  } else if (t < 131072) {
    int l = t - 98304;
    int c = l >> 6, k = l & 63;
    ws[(k >> 2) * 2048 + c * 4 + (k & 3)] = iw[l];
  } else if (t < 131584) {
    int l = t - 131072;
    int h = l >> 6, k = l & 63;
    float acc = 0.f;
    for (int c = 0; c < 64; c++) acc += av[h * 64 + c] * iw[(h * 64 + c) * 64 + k];
    ws[32768 + h * 64 + k] = acc;
  } else if (t - 131584 < zn) {
    zp[t - 131584] = 0u;  // zero CSR count region (folded launch)
  }
}

// ================== literal-index macros (straight-line code, no dynamic indexing) ==================
#define SC1(KARR, QF, CT, KS, P)                                                        \
  { f32x4 kv_ = unpk(KARR[KS][(CT) >> 1], (CT) & 1);                                    \
    float sp_ = QF[CT][0] * kv_[0] + QF[CT][1] * kv_[1] + QF[CT][2] * kv_[2] +          \
                QF[CT][3] * kv_[3];                                                     \
    sp_ = xs16(sp_);                                                                    \
    P = ((vb >> (KS)) & 1) ? sp_ : -1e30f; }

#define PV1(VARR, CT, KS, P, ACC)                                                       \
  { f32x4 vv_ = unpk(VARR[KS][(CT) >> 1], (CT) & 1);                                    \
    _Pragma("unroll") for (int r = 0; r < 4; r++) ACC[r] = fmaf(P, vv_[r], ACC[r]); }

#define ATT_CT(KARR, VARR, QF, CT, OD)                                                  \
  {                                                                                     \
    float p0, p1, p2, p3, p4;                                                           \
    SC1(KARR, QF, CT, 0, p0); SC1(KARR, QF, CT, 1, p1); SC1(KARR, QF, CT, 2, p2);       \
    SC1(KARR, QF, CT, 3, p3); SC1(KARR, QF, CT, 4, p4);                                 \
    float mx_ = fmaxf(fmaxf(fmaxf(p0, p1), fmaxf(p2, p3)), p4);                         \
    p0 = exp2f(p0 - mx_); p1 = exp2f(p1 - mx_); p2 = exp2f(p2 - mx_);                   \
    p3 = exp2f(p3 - mx_); p4 = exp2f(p4 - mx_);                                         \
    float ri_ = 1.0f / (p0 + p1 + p2 + p3 + p4);                                        \
    p0 *= ri_; p1 *= ri_; p2 *= ri_; p3 *= ri_; p4 *= ri_;                              \
    OD = (f32x4){0.f, 0.f, 0.f, 0.f};                                                   \
    PV1(VARR, CT, 0, p0, OD); PV1(VARR, CT, 1, p1, OD); PV1(VARR, CT, 2, p2, OD);       \
    PV1(VARR, CT, 3, p3, OD); PV1(VARR, CT, 4, p4, OD);                                 \
  }

#define KV_STAGE(S)                                                                     \
  {                                                                                     \
    f32x4 t[4], y[4];                                                                   \
    const bool vd = (vb >> (S)) & 1;                                                    \
    const float* fp = features + (size_t)min(ids[S], N - 1) * 64;                       \
    _Pragma("unroll")                                                                   \
    for (int ct = 0; ct < 4; ct++) {                                                    \
      f32x4 f = ld4(fp + 16 * ct + 4 * quad);                                           \
      f32x4 pv = ld4(pos_emb + (S) * 64 + 16 * ct + 4 * quad);                          \
      _Pragma("unroll")                                                                 \
      for (int r = 0; r < 4; r++) t[ct][r] = vd ? (f[r] + pv[r]) : 0.f;                 \
    }                                                                                   \
    lnT(t, y, sa_ln1_g, sa_ln1_b, quad);                                                \
    bf16x8 xl0 = mkpair(y[0], y[1]), xl1 = mkpair(y[2], y[3]);                          \
    f32x4 kt[4], vt[4];                                                                 \
    _Pragma("unroll")                                                                   \
    for (int ct = 0; ct < 4; ct++) {                                                    \
      f32x4 c = {0.f, 0.f, 0.f, 0.f};                                                   \
      c = MF(WSI[((4 + ct) * 2 + 0) * 64 + lane], xl0, c);                              \
      c = MF(WSI[((4 + ct) * 2 + 1) * 64 + lane], xl1, c);                              \
      f32x4 bb = ld4(self_in_b + 64 + 16 * ct + 4 * quad);                              \
      _Pragma("unroll")                                                                 \
      for (int r = 0; r < 4; r++) kt[ct][r] = c[r] + bb[r];                             \
      f32x4 c2 = {0.f, 0.f, 0.f, 0.f};                                                  \
      c2 = MF(WSI[((8 + ct) * 2 + 0) * 64 + lane], xl0, c2);                            \
      c2 = MF(WSI[((8 + ct) * 2 + 1) * 64 + lane], xl1, c2);                            \
      f32x4 bb2 = ld4(self_in_b + 128 + 16 * ct + 4 * quad);                            \
      _Pragma("unroll")                                                                 \
      for (int r = 0; r < 4; r++) vt[ct][r] = c2[r] + bb2[r];                           \
    }                                                                                   \
    Kp[S][0] = mkpair(kt[0], kt[1]); Kp[S][1] = mkpair(kt[2], kt[3]);                   \
    Vp[S][0] = mkpair(vt[0], vt[1]); Vp[S][1] = mkpair(vt[2], vt[3]);                   \
  }

#define Q_STAGE(S)                                                                      \
  {                                                                                     \
    const bool vd = (vb >> (S)) & 1;                                                    \
    const float* fp = features + (size_t)min(ids[S], N - 1) * 64;                       \
    f32x4 t[4], y[4];                                                                   \
    _Pragma("unroll")                                                                   \
    for (int ct = 0; ct < 4; ct++) {                                                    \
      f32x4 f = ld4(fp + 16 * ct + 4 * quad);                                           \
      f32x4 pv = ld4(pos_emb + (S) * 64 + 16 * ct + 4 * quad);                          \
      _Pragma("unroll")                                                                 \
      for (int r = 0; r < 4; r++) t[ct][r] = vd ? (f[r] + pv[r]) : 0.f;                 \
    }                                                                                   \
    lnT(t, y, sa_ln1_g, sa_ln1_b, quad);                                                \
    bf16x8 xl0 = mkpair(y[0], y[1]), xl1 = mkpair(y[2], y[3]);                          \
    f32x4 qf[4];                                                                        \
    _Pragma("unroll")                                                                   \
    for (int ct = 0; ct < 4; ct++) {                                                    \
      f32x4 c = {0.f, 0.f, 0.f, 0.f};                                                   \
      c = MF(WSI[(ct * 2 + 0) * 64 + lane], xl0, c);                                    \
      c = MF(WSI[(ct * 2 + 1) * 64 + lane], xl1, c);                                    \
      f32x4 bb = ld4(self_in_b + 16 * ct + 4 * quad);                                   \
      _Pragma("unroll")                                                                 \
      for (int r = 0; r < 4; r++) qf[ct][r] = (c[r] + bb[r]) * QSCALE;                  \
    }                                                                                   \
    f32x4 oa0, oa1, oa2, oa3;                                                           \
    ATT_CT(Kp, Vp, qf, 0, oa0); ATT_CT(Kp, Vp, qf, 1, oa1);                             \
    ATT_CT(Kp, Vp, qf, 2, oa2); ATT_CT(Kp, Vp, qf, 3, oa3);                             \
    bf16x8 op0 = mkpair(oa0, oa1), op1 = mkpair(oa2, oa3);                              \
    f32x4 tpc[4];                                                                       \
    _Pragma("unroll")                                                                   \
    for (int ct = 0; ct < 4; ct++) {                                                    \
      f32x4 c = {0.f, 0.f, 0.f, 0.f};                                                   \
      c = MF(WSO[(ct * 2 + 0) * 64 + lane], op0, c);                                    \
      c = MF(WSO[(ct * 2 + 1) * 64 + lane], op1, c);                                    \
      f32x4 bb = ld4(self_out_b + 16 * ct + 4 * quad);                                  \
      _Pragma("unroll")                                                                 \
      for (int r = 0; r < 4; r++) {                                                     \
        float tp_ = c[r] + bb[r] + t[ct][r];                                            \
        tpc[ct][r] = tp_;                                                               \
        pool[ct][r] += vd ? tp_ : 0.f;                                                  \
      }                                                                                 \
    }                                                                                   \
    TP[S][0] = mkpair(tpc[0], tpc[1]); TP[S][1] = mkpair(tpc[2], tpc[3]);               \
  }

#define CKV_STAGE(S)                                                                    \
  {                                                                                     \
    f32x4 kt[4], vt[4];                                                                 \
    _Pragma("unroll")                                                                   \
    for (int ct = 0; ct < 4; ct++) {                                                    \
      f32x4 c = {0.f, 0.f, 0.f, 0.f};                                                   \
      c = MF(WCI[((4 + ct) * 2 + 0) * 64 + lane], TP[S][0], c);                         \
      c = MF(WCI[((4 + ct) * 2 + 1) * 64 + lane], TP[S][1], c);                         \
      f32x4 bb = ld4(cross_in_b + 64 + 16 * ct + 4 * quad);                             \
      _Pragma("unroll")                                                                 \
      for (int r = 0; r < 4; r++) kt[ct][r] = c[r] + bb[r];                             \
      f32x4 c2 = {0.f, 0.f, 0.f, 0.f};                                                  \
      c2 = MF(WCI[((8 + ct) * 2 + 0) * 64 + lane], TP[S][0], c2);                       \
      c2 = MF(WCI[((8 + ct) * 2 + 1) * 64 + lane], TP[S][1], c2);                       \
      f32x4 bb2 = ld4(cross_in_b + 128 + 16 * ct + 4 * quad);                           \
      _Pragma("unroll")                                                                 \
      for (int r = 0; r < 4; r++) vt[ct][r] = c2[r] + bb2[r];                           \
    }                                                                                   \
    Kc[S][0] = mkpair(kt[0], kt[1]); Kc[S][1] = mkpair(kt[2], kt[3]);                   \
    Vc[S][0] = mkpair(vt[0], vt[1]); Vc[S][1] = mkpair(vt[2], vt[3]);                   \
  }

#define FF_H2(CT, HD)                                                                   \
  { f32x4 c = {0.f, 0.f, 0.f, 0.f};                                                     \
    c = MF(W1[((CT) * 2 + 0) * 64 + lane], x0, c);                                      \
    c = MF(W1[((CT) * 2 + 1) * 64 + lane], x1, c);                                      \
    f32x4 bb = ld4(b1 + 16 * (CT) + 4 * quad);                                          \
    _Pragma("unroll")                                                                   \
    for (int r = 0; r < 4; r++) {                                                       \
      float v = c[r] + bb[r];                                                           \
      HD[r] = 0.5f * v * (1.0f + erff(v * 0.70710678118654752440f));                    \
    } }

#define FF_O(CT)                                                                        \
  { f32x4 c = {0.f, 0.f, 0.f, 0.f};                                                     \
    c = MF(W2[((CT) * 8 + 0) * 64 + lane], Hp0, c);                                     \
    c = MF(W2[((CT) * 8 + 1) * 64 + lane], Hp1, c);                                     \
    c = MF(W2[((CT) * 8 + 2) * 64 + lane], Hp2, c);                                     \
    c = MF(W2[((CT) * 8 + 3) * 64 + lane], Hp3, c);                                     \
    c = MF(W2[((CT) * 8 + 4) * 64 + lane], Hp4, c);                                     \
    c = MF(W2[((CT) * 8 + 5) * 64 + lane], Hp5, c);                                     \
    c = MF(W2[((CT) * 8 + 6) * 64 + lane], Hp6, c);                                     \
    c = MF(W2[((CT) * 8 + 7) * 64 + lane], Hp7, c);                                     \
    f32x4 bb = ld4(b2 + 16 * (CT) + 4 * quad);                                          \
    _Pragma("unroll")                                                                   \
    for (int r = 0; r < 4; r++) inst[CT][r] += c[r] + bb[r]; }

__device__ __forceinline__ void ffnT(f32x4 (&inst)[4],
                                     const float* __restrict__ g, const float* __restrict__ b,
                                     const bf16x8* __restrict__ W1, const bf16x8* __restrict__ W2,
                                     const float* __restrict__ b1, const float* __restrict__ b2,
                                     int lane, int quad) {
  f32x4 y[4];
  lnT(inst, y, g, b, quad);
  bf16x8 x0 = mkpair(y[0], y[1]), x1 = mkpair(y[2], y[3]);
  f32x4 ha, hb;
  FF_H2(0, ha);  FF_H2(1, hb);  bf16x8 Hp0 = mkpair(ha, hb);
  FF_H2(2, ha);  FF_H2(3, hb);  bf16x8 Hp1 = mkpair(ha, hb);
  FF_H2(4, ha);  FF_H2(5, hb);  bf16x8 Hp2 = mkpair(ha, hb);
  FF_H2(6, ha);  FF_H2(7, hb);  bf16x8 Hp3 = mkpair(ha, hb);
  FF_H2(8, ha);  FF_H2(9, hb);  bf16x8 Hp4 = mkpair(ha, hb);
  FF_H2(10, ha); FF_H2(11, hb); bf16x8 Hp5 = mkpair(ha, hb);
  FF_H2(12, ha); FF_H2(13, hb); bf16x8 Hp6 = mkpair(ha, hb);
  FF_H2(14, ha); FF_H2(15, hb); bf16x8 Hp7 = mkpair(ha, hb);
  FF_O(0); FF_O(1); FF_O(2); FF_O(3);
}

#define ASC(H)                                                                          \
  { float sp = 0.f;                                                                     \
    _Pragma("unroll")                                                                   \
    for (int ct = 0; ct < 4; ct++) {                                                    \
      f32x4 uu = ld4(uvec + (H) * 64 + 16 * ct + 4 * quad);                             \
      _Pragma("unroll")                                                                 \
      for (int r = 0; r < 4; r++) sp = fmaf(inst[ct][r], uu[r], sp);                    \
    }                                                                                   \
    sp = qsum(sp);                                                                      \
    a##H = sp > 0.f ? sp : 0.01f * sp; }

// ---------- per-edge transformer: one wave = 16 edges, fully register-resident ----------
// (64,1): 512-reg budget, VGPR 252, ZERO spill (rounds 7/8/9/11/13). Closed directions:
//  * (64,2): arch regs capped 128 -> ~700MB scratch (rounds 0-2, 10)
//  * 32 edges/wave: arch-VGPR hard cap 256 -> spill (round 12)
//  * VALU reduction: no latency effect (round 7; chain/latency-bound)
__global__ __launch_bounds__(64, 1)
void edge_kernel(const float* __restrict__ features, const float* __restrict__ pos_emb,
                 const float* __restrict__ self_in_b, const float* __restrict__ self_out_b,
                 const float* __restrict__ cross_in_b, const float* __restrict__ cross_out_b,
                 const float* __restrict__ sa_ln1_g, const float* __restrict__ sa_ln1_b,
                 const float* __restrict__ sa_ln2_g, const float* __restrict__ sa_ln2_b,
                 const float* __restrict__ ca_ln1_g, const float* __restrict__ ca_ln1_b,
                 const float* __restrict__ ca_ln2_g, const float* __restrict__ ca_ln2_b,
                 const float* __restrict__ sa_ff_b1, const float* __restrict__ sa_ff_b2,
                 const float* __restrict__ ca_ff_b1, const float* __restrict__ ca_ff_b2,
                 const int* __restrict__ midx, const int* __restrict__ dstv,
                 const float* __restrict__ ws,
                 float* __restrict__ inst_out, float* __restrict__ a_out, int E, int N) {
  const int lane = threadIdx.x;
  const int quad = lane >> 4, lo = lane & 15;
  const int e0 = blockIdx.x * 16;
  __shared__ float xp[16 * 68];

  const ushort_t* bw = (const ushort_t*)(ws + 33280);
  const bf16x8* WSI = (const bf16x8*)(bw);
  const bf16x8* WSO = (const bf16x8*)(bw + 12288);
  const bf16x8* W1S = (const bf16x8*)(bw + 16384);
  const bf16x8* W2S = (const bf16x8*)(bw + 32768);
  const bf16x8* WCI = (const bf16x8*)(bw + 49152);
  const bf16x8* WCO = (const bf16x8*)(bw + 61440);
  const bf16x8* W1C = (const bf16x8*)(bw + 65536);
  const bf16x8* W2C = (const bf16x8*)(bw + 81920);
  const float* uvec = ws + 32768;

  const bool ge = (e0 + lo) < E;
  const int eIdx = min(e0 + lo, E - 1);
  int ids[5];
  ids[0] = midx[eIdx * 5 + 0];
  ids[1] = midx[eIdx * 5 + 1];
  ids[2] = midx[eIdx * 5 + 2];
  ids[3] = midx[eIdx * 5 + 3];
  ids[4] = midx[eIdx * 5 + 4];
  int vb = 0;
  if (ids[0] != N && ge) vb |= 1;
  if (ids[1] != N && ge) vb |= 2;
  if (ids[2] != N && ge) vb |= 4;
  if (ids[3] != N && ge) vb |= 8;
  if (ids[4] != N && ge) vb |= 16;
  const int nv = __popc(vb);
  const int lp = max(nv - 1, 0);
  int lid = ids[0];
  lid = (lp == 1) ? ids[1] : lid;
  lid = (lp == 2) ? ids[2] : lid;
  lid = (lp == 3) ? ids[3] : lid;
  lid = (lp == 4) ? ids[4] : lid;

  bf16x8 Kp[5][2], Vp[5][2];
  KV_STAGE(0); KV_STAGE(1); KV_STAGE(2); KV_STAGE(3); KV_STAGE(4);

  f32x4 pool[4];
#pragma unroll
  for (int ct = 0; ct < 4; ct++) pool[ct] = (f32x4){0.f, 0.f, 0.f, 0.f};
  bf16x8 TP[5][2];
  Q_STAGE(0); Q_STAGE(1); Q_STAGE(2); Q_STAGE(3); Q_STAGE(4);

  f32x4 inst[4];
  {
    float rn = 1.0f / (float)max(nv, 1);
#pragma unroll
    for (int ct = 0; ct < 4; ct++)
#pragma unroll
      for (int r = 0; r < 4; r++) inst[ct][r] = pool[ct][r] * rn;
  }

  ffnT(inst, sa_ln2_g, sa_ln2_b, W1S, W2S, sa_ff_b1, sa_ff_b2, lane, quad);

  {
    f32x4 tf[4], xq[4];
    const bool vdl = lid != N;
    const float* fp = features + (size_t)min(lid, N - 1) * 64;
#pragma unroll
    for (int ct = 0; ct < 4; ct++) {
      f32x4 f = ld4(fp + 16 * ct + 4 * quad);
#pragma unroll
      for (int r = 0; r < 4; r++) tf[ct][r] = vdl ? f[r] : 0.f;
    }
    lnT(tf, xq, ca_ln1_g, ca_ln1_b, quad);
    bf16x8 xq0 = mkpair(xq[0], xq[1]), xq1 = mkpair(xq[2], xq[3]);
    f32x4 qcf[4];
#pragma unroll
    for (int ct = 0; ct < 4; ct++) {
      f32x4 c = {0.f, 0.f, 0.f, 0.f};
      c = MF(WCI[(ct * 2 + 0) * 64 + lane], xq0, c);
      c = MF(WCI[(ct * 2 + 1) * 64 + lane], xq1, c);
      f32x4 bb = ld4(cross_in_b + 16 * ct + 4 * quad);
#pragma unroll
      for (int r = 0; r < 4; r++) qcf[ct][r] = (c[r] + bb[r]) * QSCALE;
    }
    bf16x8 Kc[5][2], Vc[5][2];
    CKV_STAGE(0); CKV_STAGE(1); CKV_STAGE(2); CKV_STAGE(3); CKV_STAGE(4);
    f32x4 cc0, cc1, cc2, cc3;
    ATT_CT(Kc, Vc, qcf, 0, cc0); ATT_CT(Kc, Vc, qcf, 1, cc1);
    ATT_CT(Kc, Vc, qcf, 2, cc2); ATT_CT(Kc, Vc, qcf, 3, cc3);
    bf16x8 cp0 = mkpair(cc0, cc1), cp1 = mkpair(cc2, cc3);
#pragma unroll
    for (int ct = 0; ct < 4; ct++) {
      f32x4 c = {0.f, 0.f, 0.f, 0.f};
      c = MF(WCO[(ct * 2 + 0) * 64 + lane], cp0, c);
      c = MF(WCO[(ct * 2 + 1) * 64 + lane], cp1, c);
      f32x4 bb = ld4(cross_out_b + 16 * ct + 4 * quad);
#pragma unroll
      for (int r = 0; r < 4; r++) inst[ct][r] += c[r] + bb[r];
    }
  }

  ffnT(inst, ca_ln2_g, ca_ln2_b, W1C, W2C, ca_ff_b1, ca_ff_b2, lane, quad);

  float a0, a1, a2, a3, a4, a5, a6, a7;
  ASC(0); ASC(1); ASC(2); ASC(3); ASC(4); ASC(5); ASC(6); ASC(7);
  if (ge && quad < 2) {
    f32x4 st = (quad == 0) ? (f32x4){a0, a1, a2, a3} : (f32x4){a4, a5, a6, a7};
    *(f32x4*)(a_out + (size_t)(e0 + lo) * 8 + 4 * quad) = st;
  }

#pragma unroll
  for (int ct = 0; ct < 4; ct++)
    *(f32x4*)(&xp[lo * 68 + 16 * ct + 4 * quad]) = inst[ct];
  __syncthreads();
  {
    int er = lane >> 2, cb = (lane & 3) * 16;
    if (e0 + er < E) {
#pragma unroll
      for (int u = 0; u < 4; u++) {
        f32x4 v = *(const f32x4*)(&xp[er * 68 + cb + 4 * u]);
        *(f32x4*)(inst_out + (size_t)(e0 + er) * 64 + cb + 4 * u) = v;
      }
    }
  }
}

// ================== CSR-by-dst build (parallel 3-phase scan; single-block fused scan
// regressed ~90us in round 10 — serial barriers on one CU) ==================
__global__ void csr_count_kernel(const int* __restrict__ dstv, unsigned int* __restrict__ cnt,
                                 int E) {
  int e = blockIdx.x * blockDim.x + threadIdx.x;
  if (e < E) atomicAdd(&cnt[dstv[e]], 1u);
}

__global__ void scan1_kernel(unsigned int* __restrict__ off, unsigned int* __restrict__ bsum,
                             int N) {
  __shared__ unsigned int sd[256];
  int t = threadIdx.x, n = blockIdx.x * 256 + t;
  unsigned int v = (n < N) ? off[n] : 0u;
  sd[t] = v;
  __syncthreads();
  for (int o = 1; o < 256; o <<= 1) {
    unsigned int x = (t >= o) ? sd[t - o] : 0u;
    __syncthreads();
    sd[t] += x;
    __syncthreads();
  }
  if (n < N) off[n] = sd[t] - v;  // local exclusive
  if (t == 255) bsum[blockIdx.x] = sd[255];
}

__global__ void scan2_kernel(unsigned int* __restrict__ bsum, int nb) {
  __shared__ unsigned int sd[1024];
  int t = threadIdx.x;
  unsigned int v = (t < nb) ? bsum[t] : 0u;
  sd[t] = v;
  __syncthreads();
  for (int o = 1; o < 1024; o <<= 1) {
    unsigned int x = (t >= o) ? sd[t - o] : 0u;
    __syncthreads();
    sd[t] += x;
    __syncthreads();
  }
  if (t < nb) bsum[t] = sd[t] - v;  // exclusive
}

__global__ void scan3_kernel(unsigned int* __restrict__ off, unsigned int* __restrict__ cur,
                             const unsigned int* __restrict__ bsum, int N, int E) {
  int n = blockIdx.x * 256 + threadIdx.x;
  if (n < N) {
    unsigned int o = off[n] + bsum[blockIdx.x];
    off[n] = o;
    cur[n] = o;
  }
  if (n == 0) off[N] = (unsigned int)E;
}

__global__ void csr_fill_kernel(const int* __restrict__ dstv, unsigned int* __restrict__ cur,
                                unsigned int* __restrict__ elist, int E) {
  int e = blockIdx.x * blockDim.x + threadIdx.x;
  if (e < E) {
    unsigned int p = atomicAdd(&cur[dstv[e]], 1u);
    elist[p] = (unsigned int)e;
  }
}

// ================== per-node edge-softmax: a[e][0..7] -> unnormalized w, sinv[n][0..7]=1/s ==================
__global__ __launch_bounds__(256)
void att_kernel(const unsigned int* __restrict__ off, const unsigned int* __restrict__ elist,
                float* __restrict__ a, float* __restrict__ sinv, int N) {
  int n = blockIdx.x * blockDim.x + threadIdx.x;
  if (n >= N) return;
  const unsigned int s0 = off[n], s1 = off[n + 1];
  f32x4 m0 = {-3.0e38f, -3.0e38f, -3.0e38f, -3.0e38f}, m1 = m0;
  for (unsigned int i = s0; i < s1; i++) {
    const float* ap = a + (size_t)elist[i] * 8;
    f32x4 x0 = ld4(ap), x1 = ld4(ap + 4);
#pragma unroll
    for (int r = 0; r < 4; r++) { m0[r] = fmaxf(m0[r], x0[r]); m1[r] = fmaxf(m1[r], x1[r]); }
  }
  f32x4 t0 = {0.f, 0.f, 0.f, 0.f}, t1 = t0;
  for (unsigned int i = s0; i < s1; i++) {
    float* ap = a + (size_t)elist[i] * 8;
    f32x4 x0 = ld4(ap), x1 = ld4(ap + 4);
    f32x4 w0, w1;
#pragma unroll
    for (int r = 0; r < 4; r++) {
      w0[r] = __expf(x0[r] - m0[r]);
      w1[r] = __expf(x1[r] - m1[r]);
      t0[r] += w0[r];
      t1[r] += w1[r];
    }
    *(f32x4*)ap = w0;
    *(f32x4*)(ap + 4) = w1;
  }
  f32x4 r0, r1;
#pragma unroll
  for (int r = 0; r < 4; r++) {
    r0[r] = (t0[r] > 0.f) ? 1.0f / t0[r] : 0.f;
    r1[r] = (t1[r] > 0.f) ? 1.0f / t1[r] : 0.f;
  }
  *(f32x4*)(sinv + (size_t)n * 8) = r0;
  *(f32x4*)(sinv + (size_t)n * 8 + 4) = r1;
}

// ================== fused gather: 8 h-waves per block share one node range ==================
// v3: all 8 heads of a node processed by co-resident waves (block = 512 thr, wave h =
// tid>>6). inst_emb row + a/elist lines are read by all 8 waves within a few hundred
// cycles -> 7/8 reads hit L1/L2 instead of L3 (was: h = blockIdx.y, unrelated CUs/times,
// 8 x 150k x 256B = 307MB of L3 reads). Math identical per (n,h).
__global__ __launch_bounds__(512)
void gather_kernel(const float* __restrict__ T_iw, const unsigned int* __restrict__ off,
                   const unsigned int* __restrict__ elist, const float* __restrict__ a,
                   const float* __restrict__ sinv, const float* __restrict__ inst_emb,
                   float* __restrict__ out, int N) {
  const int lane = threadIdx.x & 63;
  const int h = threadIdx.x >> 6;  // 0..7: one wave per head
  const vf4* P = (const vf4*)T_iw;
  vf4 wr[16];
#pragma unroll
  for (int k = 0; k < 16; k++) wr[k] = P[k * 512 + h * 64 + lane];  // W_h[lane][4k..4k+3]
  const int stride = gridDim.x;
  for (int n = blockIdx.x; n < N; n += stride) {
    const unsigned int s0 = off[n], s1 = off[n + 1];
    float z = 0.f;
    for (unsigned int i = s0; i < s1; i++) {
      unsigned int e = elist[i];
      z = fmaf(a[(size_t)e * 8 + h], inst_emb[(size_t)e * 64 + lane], z);
    }
    z *= sinv[(size_t)n * 8 + h];
    float o = 0.f;
#pragma unroll
    for (int k = 0; k < 16; k++) {
#pragma unroll
      for (int u = 0; u < 4; u++) o = fmaf(bcast(z, k * 4 + u), wr[k][u], o);
    }
    out[(size_t)n * 512 + h * 64 + lane] = o;
  }
}

extern "C" void kernel_launch(void* const* d_in, const int* in_sizes, int n_in,
                              void* d_out, int out_size, void* d_ws, size_t ws_size,
                              hipStream_t stream) {
  const float* features   = (const float*)d_in[0];
  const float* pos_emb    = (const float*)d_in[1];
  const float* self_in_w  = (const float*)d_in[2];
  const float* self_in_b  = (const float*)d_in[3];
  const float* self_out_w = (const float*)d_in[4];
  const float* self_out_b = (const float*)d_in[5];
  const float* cross_in_w = (const float*)d_in[6];
  const float* cross_in_b = (const float*)d_in[7];
  const float* cross_out_w= (const float*)d_in[8];
  const float* cross_out_b= (const float*)d_in[9];
  const float* sa_ln1_g = (const float*)d_in[10];
  const float* sa_ln1_b = (const float*)d_in[11];
  const float* sa_ln2_g = (const float*)d_in[12];
  const float* sa_ln2_b = (const float*)d_in[13];
  const float* ca_ln1_g = (const float*)d_in[14];
  const float* ca_ln1_b = (const float*)d_in[15];
  const float* ca_ln2_g = (const float*)d_in[16];
  const float* ca_ln2_b = (const float*)d_in[17];
  const float* sa_ff_w1 = (const float*)d_in[18];
  const float* sa_ff_b1 = (const float*)d_in[19];
  const float* sa_ff_w2 = (const float*)d_in[20];
  const float* sa_ff_b2 = (const float*)d_in[21];
  const float* ca_ff_w1 = (const float*)d_in[22];
  const float* ca_ff_b1 = (const float*)d_in[23];
  const float* ca_ff_w2 = (const float*)d_in[24];
  const float* ca_ff_b2 = (const float*)d_in[25];
  const float* inst_w   = (const float*)d_in[26];
  const float* attn_vec = (const float*)d_in[27];
  const int* midx = (const int*)d_in[28];
  const int* dstv = (const int*)d_in[29];

  const int N = in_sizes[0] / 64;
  const int E = in_sizes[29];

  // ws floats: [0..32767] T_iw | [32768..33279] u | [33280..82431] bf16 A-frag packs
  //            [131072...] inst_emb[E*64] | a[E*8] | off[N+1] | cur[N] | bsum[1024]
  //            | elist[E] | sinv[N*8]
  float* wsf = (float*)d_ws;
  float* inst_emb = wsf + 131072;
  float* a_arr = inst_emb + (size_t)E * 64;
  unsigned int* off = (unsigned int*)(a_arr + (size_t)E * 8);
  unsigned int* cur = off + (size_t)(N + 1);
  unsigned int* bsum = cur + (size_t)N;
  unsigned int* elist = bsum + 1024;
  float* sinv = (float*)(elist + (size_t)E);

  const int nb1 = (N + 255) / 256;

  // prep + zero CSR count region (folded: saves one launch)
  int zn = N + 1;
  prep_kernel<<<(131584 + zn + 255) / 256, 256, 0, stream>>>(
      self_in_w, self_out_w, sa_ff_w1, sa_ff_w2, cross_in_w, cross_out_w, ca_ff_w1, ca_ff_w2,
      inst_w, attn_vec, wsf, off, zn);

  // CSR build (independent of edge_kernel results)
  csr_count_kernel<<<(E + 255) / 256, 256, 0, stream>>>(dstv, off, E);
  scan1_kernel<<<nb1, 256, 0, stream>>>(off, bsum, N);
  scan2_kernel<<<1, 1024, 0, stream>>>(bsum, nb1);
  scan3_kernel<<<nb1, 256, 0, stream>>>(off, cur, bsum, N, E);
  csr_fill_kernel<<<(E + 255) / 256, 256, 0, stream>>>(dstv, cur, elist, E);

  int nblk = (E + 15) / 16;  // 1 wave/block, 16 edges/wave
  edge_kernel<<<nblk, 64, 0, stream>>>(
      features, pos_emb, self_in_b, self_out_b, cross_in_b, cross_out_b, sa_ln1_g, sa_ln1_b,
      sa_ln2_g, sa_ln2_b, ca_ln1_g, ca_ln1_b, ca_ln2_g, ca_ln2_b, sa_ff_b1, sa_ff_b2, ca_ff_b1,
      ca_ff_b2, midx, dstv, wsf, inst_emb, a_arr, E, N);

  att_kernel<<<(N + 255) / 256, 256, 0, stream>>>(off, elist, a_arr, sinv, N);

  gather_kernel<<<2048, 512, 0, stream>>>(wsf, off, elist, a_arr, sinv, inst_emb,
                                          (float*)d_out, N);
}